// Round 4
// baseline (2511.844 us; speedup 1.0000x reference)
//
#include <hip/hip_runtime.h>
#include <stdint.h>

typedef unsigned short u16;
typedef unsigned int u32;

using bf8_t = __attribute__((ext_vector_type(8))) short;   // 8 bf16 (bit patterns)
using f4_t  = __attribute__((ext_vector_type(4))) float;

#define MFMA16(a,b,c) __builtin_amdgcn_mfma_f32_16x16x32_bf16((a),(b),(c),0,0,0)

__device__ __forceinline__ u16 f2bf(float f) {      // RNE
  union { float f; u32 u; } v; v.f = f;
  u32 u = v.u;
  u += 0x7FFFu + ((u >> 16) & 1u);
  return (u16)(u >> 16);
}
__device__ __forceinline__ u16 f2bf_t(float f) {    // truncate (lo residuals only)
  union { float f; u32 u; } v; v.f = f;
  return (u16)(v.u >> 16);
}
__device__ __forceinline__ float bf2f(u16 h) {
  union { float f; u32 u; } v; v.u = ((u32)h) << 16; return v.f;
}
__device__ __forceinline__ float sigm(float x) {
  return __builtin_amdgcn_rcpf(1.f + __expf(-x));
}
__device__ __forceinline__ float tanh_f(float x) {
  x = fminf(30.f, fmaxf(-30.f, x));
  float e = __expf(-2.f * x);
  return (1.f - e) * __builtin_amdgcn_rcpf(1.f + e);
}

// Barrier WITHOUT vmem drain: only LDS (lgkm) must be visible across waves.
// Global loads in flight (register-destined prefetches) legally cross it.
__device__ __forceinline__ void block_sync_lds() {
  __builtin_amdgcn_sched_barrier(0);
  asm volatile("s_waitcnt lgkmcnt(0)\n\ts_barrier" ::: "memory");
  __builtin_amdgcn_sched_barrier(0);
}

// ---------------- prep kernels ----------------

__global__ void k_gemm128(const float* __restrict__ A, const float* __restrict__ B,
                          float* __restrict__ C) {
  int g = blockIdx.x * 256 + threadIdx.x;
  int row = g >> 5;
  int c0 = (g & 31) << 2;
  f4_t acc = {0.f, 0.f, 0.f, 0.f};
  for (int k = 0; k < 128; ++k) {
    float a = A[row * 128 + k];
    acc += a * *(const f4_t*)&B[k * 128 + c0];
  }
  *(f4_t*)&C[row * 128 + c0] = acc;
}

__global__ void k_wbig(const float* __restrict__ fc_W, const float* __restrict__ B2,
                       const float* __restrict__ B3, float* __restrict__ WB) {
  int g = blockIdx.x * 256 + threadIdx.x;
  int row = g / 96;
  int j0 = (g % 96) * 4;
  if (j0 < 128) {
    *(f4_t*)&WB[row * 384 + j0] = *(const f4_t*)&fc_W[row * 128 + j0];
  } else {
    const float* Bm = (j0 < 256) ? B2 : B3;
    int jj = j0 & 127;
    f4_t acc = {0.f, 0.f, 0.f, 0.f};
    for (int n = 0; n < 128; ++n)
      acc += fc_W[row * 128 + n] * *(const f4_t*)&Bm[n * 128 + jj];
    *(f4_t*)&WB[row * 384 + j0] = acc;
  }
}

__global__ void k_bbig(const float* __restrict__ fc_b, const float* __restrict__ fc2_b,
                       const float* __restrict__ B2, const float* __restrict__ B3,
                       const float* __restrict__ Wq2, const float* __restrict__ Wk3,
                       float* __restrict__ bb) {
  int j = blockIdx.x * 256 + threadIdx.x;
  if (j >= 384) return;
  if (j < 128) { bb[j] = fc_b[j]; return; }
  const float* Bm = (j < 256) ? B2 : B3;
  const float* Wm = (j < 256) ? Wq2 : Wk3;
  int jj = j & 127;
  float acc = 0.f;
  for (int n = 0; n < 128; ++n)
    acc += fc_b[n] * Bm[n * 128 + jj] + fc2_b[n] * Wm[n * 128 + jj];
  bb[j] = acc;
}

__global__ void k_skdf(const float* __restrict__ skill_emb, const float* __restrict__ diff_emb,
                       const float* __restrict__ WB, const float* __restrict__ bb,
                       float* __restrict__ SK, float* __restrict__ DF) {
  int g = blockIdx.x * 256 + threadIdx.x;
  int row = g / 96, j0 = (g % 96) * 4;
  if (blockIdx.y == 0) {
    if (row >= 1002) return;
    f4_t acc = {0.f, 0.f, 0.f, 0.f};
    for (int d = 0; d < 128; ++d)
      acc += skill_emb[row * 128 + d] * *(const f4_t*)&WB[d * 384 + j0];
    *(f4_t*)&SK[row * 384 + j0] = acc;
  } else {
    if (row >= 102) return;
    f4_t acc = *(const f4_t*)&bb[j0];
    for (int d = 0; d < 128; ++d)
      acc += diff_emb[row * 128 + d] * *(const f4_t*)&WB[(128 + d) * 384 + j0];
    *(f4_t*)&DF[row * 384 + j0] = acc;
  }
}

__global__ void k_tv(const float* __restrict__ hints_emb, const float* __restrict__ Wv2,
                     const float* __restrict__ answer_emb, const float* __restrict__ Wv3,
                     float* __restrict__ Tv2, float* __restrict__ Tv3) {
  int g = blockIdx.x * 256 + threadIdx.x;
  if (g < 384) {
    int i = g >> 5, j0 = (g & 31) << 2;
    f4_t acc = {0.f, 0.f, 0.f, 0.f};
    for (int d = 0; d < 128; ++d)
      acc += hints_emb[i * 128 + d] * *(const f4_t*)&Wv2[d * 128 + j0];
    *(f4_t*)&Tv2[i * 128 + j0] = acc;
  } else if (g < 480) {
    int g2 = g - 384;
    int i = g2 >> 5, j0 = (g2 & 31) << 2;
    f4_t acc = {0.f, 0.f, 0.f, 0.f};
    for (int d = 0; d < 128; ++d)
      acc += answer_emb[i * 128 + d] * *(const f4_t*)&Wv3[d * 128 + j0];
    *(f4_t*)&Tv3[i * 128 + j0] = acc;
  }
}

// Pack in-loop weights into per-lane MFMA A-fragment order.
// whi layout (register-resident hi):  idx = (((m*4+kk)*8+w)*64+lane)*8
// flo layout (streamed lo, per-wave contiguous):
//   phase = m>>2, mm = m&3 ; idx = ((((phase*8+w)*16)+(mm*4+kk))*64+lane)*8
struct P8 { const float* p[8]; };
__global__ void k_pack(P8 s, u16* __restrict__ whi, u16* __restrict__ flo) {
  int g = blockIdx.x * 256 + threadIdx.x;   // 128*256 = 32768
  bool lo = (g >= 16384);
  int gg = g & 16383;
  int m = gg >> 11;
  int r = gg & 2047;
  int kk = r >> 9, w = (r >> 6) & 7, l = r & 63;
  const float* src = s.p[m];
  int col = w * 16 + (l & 15);
  int kbase = kk * 32 + ((l >> 4) << 3);
  u16 o[8];
  #pragma unroll
  for (int e = 0; e < 8; ++e) {
    float v = src[(kbase + e) * 128 + col];
    u16 h = f2bf(v);
    o[e] = lo ? f2bf(v - bf2f(h)) : h;
  }
  u16* dst;
  if (!lo) {
    dst = whi + gg * 8;
  } else {
    int phase = m >> 2, mm = m & 3;
    dst = flo + ((((phase * 8 + w) * 16) + (mm * 4 + kk)) * 64 + l) * 8;
  }
  uint4 u;
  u.x = o[0] | ((u32)o[1] << 16); u.y = o[2] | ((u32)o[3] << 16);
  u.z = o[4] | ((u32)o[5] << 16); u.w = o[6] | ((u32)o[7] << 16);
  *(uint4*)dst = u;
}

// ---------------- main recurrent kernel ----------------
// 32 blocks x 512 threads; block b owns batch rows 16b..16b+15.
// Wave w owns feature cols [16w,16w+16). Weight HI fragments register-resident;
// LO residuals streamed from L2 each phase. Barriers are lgkm-only (no vmem
// drain) so all global prefetches stay in flight across phases; next-step
// SK/DF fragments are issued a full phase ahead.

__launch_bounds__(512, 1)
__global__ void k_main(const int* __restrict__ skill, const int* __restrict__ answer,
                       const int* __restrict__ diff, const int* __restrict__ hints,
                       const float* __restrict__ SK, const float* __restrict__ DF,
                       const float* __restrict__ Tv2, const float* __restrict__ Tv3,
                       const u16* __restrict__ whi, const u16* __restrict__ flo,
                       const float* __restrict__ b11p, const float* __restrict__ b12p,
                       const float* __restrict__ b21p, const float* __restrict__ b22p,
                       float* __restrict__ out) {
  __shared__ u16 sh_h[2048], sh_hl[2048], sh_c[2048], sh_cl[2048];
  __shared__ u16 sh_oh[2048], sh_ol[2048], sh_o3[2048], sh_o3l[2048];
  __shared__ float sh_tv2[12 * 132];
  __shared__ float sh_tv3[3 * 132];
  __shared__ float sh_bias[512];
  __shared__ float sh_red[16 * 8];

  const int tid = threadIdx.x;
  const int w = tid >> 6, lane = tid & 63;
  const int row = lane & 15;
  const int fgrp = lane >> 4;
  const int f0 = w * 16 + fgrp * 4;
  const int row_g = blockIdx.x * 16 + row;
  const int r200 = row_g * 200;

  // persistent hi weight fragments
  bf8_t wf[8][4];
  #pragma unroll
  for (int m = 0; m < 8; ++m)
    #pragma unroll
    for (int kk = 0; kk < 4; ++kk)
      wf[m][kk] = *(const bf8_t*)&whi[(((m * 4 + kk) * 8 + w) * 64 + lane) * 8];

  // streaming bases for lo residuals (per-wave contiguous)
  const u16* lo1 = flo + (w * 16) * 512 + lane * 8;     // stage-1 mats {A2,A3,Wq3,Wk2}
  const u16* lo2 = lo1 + 8 * 16 * 512;                  // stage-2 mats {f11,f12,f21,f22}

  // LDS init
  for (int i = tid; i < 1024; i += 512) {
    ((u32*)sh_h)[i] = 0u; ((u32*)sh_hl)[i] = 0u;
    ((u32*)sh_c)[i] = 0u; ((u32*)sh_cl)[i] = 0u;
  }
  for (int i = tid; i < 12 * 128; i += 512) sh_tv2[(i >> 7) * 132 + (i & 127)] = Tv2[i];
  for (int i = tid; i < 3 * 128; i += 512) sh_tv3[(i >> 7) * 132 + (i & 127)] = Tv3[i];
  if (tid < 128) {
    sh_bias[tid]       = b11p[tid];
    sh_bias[128 + tid] = b12p[tid];
    sh_bias[256 + tid] = b21p[tid];
    sh_bias[384 + tid] = b22p[tid];
  }
  if (tid < 16) out[(blockIdx.x * 16 + tid) * 200 + 199] = 0.f;  // y[:,199] = 0

  f4_t cst = {0.f, 0.f, 0.f, 0.f};   // fp32 c state

  // rolling index prefetch
  int is_cur = skill[r200],     id_cur = diff[r200];
  int is_nxt = skill[r200 + 1], id_nxt = diff[r200 + 1];
  int ih_cur = hints[r200],     ia_cur = answer[r200];

  // loop-invariant LDS offsets (elements)
  const float inv = 0.088388347648318447f;  // 1/sqrt(128)
  const int swz = (row & 7) << 3;
  const int rbase = row * 128;
  const int widx = (rbase + f0) ^ swz;
  int roff[4];
  #pragma unroll
  for (int kk = 0; kk < 4; ++kk) roff[kk] = (rbase + kk * 32 + fgrp * 8) ^ swz;

  // prologue: step-0 S1 table fragments (normally prefetched one phase ahead)
  f4_t skq2 = *(const f4_t*)&SK[is_cur * 384 + 128 + f0];
  f4_t dfq2 = *(const f4_t*)&DF[id_cur * 384 + 128 + f0];
  f4_t skq3 = *(const f4_t*)&SK[is_cur * 384 + 256 + f0];
  f4_t dfq3 = *(const f4_t*)&DF[id_cur * 384 + 256 + f0];
  __syncthreads();

  for (int t = 0; t < 199; ++t) {
    // ---- S1 top: issue lo-streams + v2/v3 gathers ----
    bf8_t lf0[4], lf1[4], lf2m[4], lf3[4];
    #pragma unroll
    for (int kk = 0; kk < 4; ++kk) {
      lf0[kk]  = *(const bf8_t*)(lo1 + (0 * 4 + kk) * 512);
      lf1[kk]  = *(const bf8_t*)(lo1 + (1 * 4 + kk) * 512);
      lf2m[kk] = *(const bf8_t*)(lo1 + (2 * 4 + kk) * 512);
      lf3[kk]  = *(const bf8_t*)(lo1 + (3 * 4 + kk) * 512);
    }
    f4_t v2 = *(const f4_t*)&sh_tv2[ih_cur * 132 + f0];
    f4_t v3 = *(const f4_t*)&sh_tv3[ia_cur * 132 + f0];

    // ---- stage 1 hi terms: wf x {act_hi, act_lo} ----
    f4_t q2a = {0.f, 0.f, 0.f, 0.f};
    f4_t q3a = {0.f, 0.f, 0.f, 0.f};
    f4_t k3a = {0.f, 0.f, 0.f, 0.f};
    f4_t k2a = {0.f, 0.f, 0.f, 0.f};
    #pragma unroll
    for (int kk = 0; kk < 4; ++kk) {
      bf8_t hh = *(const bf8_t*)&sh_h[roff[kk]];
      bf8_t hl = *(const bf8_t*)&sh_hl[roff[kk]];
      bf8_t ch = *(const bf8_t*)&sh_c[roff[kk]];
      bf8_t cl = *(const bf8_t*)&sh_cl[roff[kk]];
      q2a = MFMA16(wf[0][kk], hh, q2a); q2a = MFMA16(wf[0][kk], hl, q2a);
      q3a = MFMA16(wf[1][kk], hh, q3a); q3a = MFMA16(wf[1][kk], hl, q3a);
      k3a = MFMA16(wf[2][kk], hh, k3a); k3a = MFMA16(wf[2][kk], hl, k3a);
      k2a = MFMA16(wf[3][kk], ch, k2a); k2a = MFMA16(wf[3][kk], cl, k2a);
    }
    // ---- stage 1 lo-weight terms ----
    #pragma unroll
    for (int kk = 0; kk < 4; ++kk) {
      bf8_t hh = *(const bf8_t*)&sh_h[roff[kk]];
      bf8_t ch = *(const bf8_t*)&sh_c[roff[kk]];
      q2a = MFMA16(lf0[kk],  hh, q2a);
      q3a = MFMA16(lf1[kk],  hh, q3a);
      k3a = MFMA16(lf2m[kk], hh, k3a);
      k2a = MFMA16(lf3[kk],  ch, k2a);
    }

    // ---- E1: gates + write out/o3 (hi+lo) to LDS ----
    u16 oh[4], ol[4], o3h[4], o3l[4];
    #pragma unroll
    for (int r = 0; r < 4; ++r) {
      float q2v = q2a[r] + skq2[r] + dfq2[r];
      float q3v = q3a[r] + skq3[r] + dfq3[r];
      float ov = v2[r] * sigm(q2v * k2a[r] * inv);
      float o3v = v3[r] * sigm(q3v * k3a[r] * inv);
      oh[r] = f2bf(ov);
      ol[r] = f2bf_t(ov - bf2f(oh[r]));
      o3h[r] = f2bf(o3v);
      o3l[r] = f2bf_t(o3v - bf2f(o3h[r]));
    }
    uint2 pk;
    pk.x = oh[0] | ((u32)oh[1] << 16); pk.y = oh[2] | ((u32)oh[3] << 16);
    *(uint2*)&sh_oh[widx] = pk;
    pk.x = ol[0] | ((u32)ol[1] << 16); pk.y = ol[2] | ((u32)ol[3] << 16);
    *(uint2*)&sh_ol[widx] = pk;
    pk.x = o3h[0] | ((u32)o3h[1] << 16); pk.y = o3h[2] | ((u32)o3h[3] << 16);
    *(uint2*)&sh_o3[widx] = pk;
    pk.x = o3l[0] | ((u32)o3l[1] << 16); pk.y = o3l[2] | ((u32)o3l[3] << 16);
    *(uint2*)&sh_o3l[widx] = pk;
    block_sync_lds();

    // ---- S2 top: issue gf streams + xn + NEXT-step S1 tables + idx ----
    bf8_t gf0[4], gf1[4], gf2[4], gf3[4];
    #pragma unroll
    for (int kk = 0; kk < 4; ++kk) {
      gf0[kk] = *(const bf8_t*)(lo2 + (0 * 4 + kk) * 512);
      gf1[kk] = *(const bf8_t*)(lo2 + (1 * 4 + kk) * 512);
      gf2[kk] = *(const bf8_t*)(lo2 + (2 * 4 + kk) * 512);
      gf3[kk] = *(const bf8_t*)(lo2 + (3 * 4 + kk) * 512);
    }
    f4_t skxn = *(const f4_t*)&SK[is_nxt * 384 + f0];
    f4_t dfxn = *(const f4_t*)&DF[id_nxt * 384 + f0];
    f4_t nskq2 = *(const f4_t*)&SK[is_nxt * 384 + 128 + f0];
    f4_t ndfq2 = *(const f4_t*)&DF[id_nxt * 384 + 128 + f0];
    f4_t nskq3 = *(const f4_t*)&SK[is_nxt * 384 + 256 + f0];
    f4_t ndfq3 = *(const f4_t*)&DF[id_nxt * 384 + 256 + f0];
    int tn = (t + 2 < 200) ? (t + 2) : 199;
    int n_s2 = skill[r200 + tn];
    int n_d2 = diff[r200 + tn];
    int n_h1 = hints[r200 + t + 1];
    int n_a1 = answer[r200 + t + 1];

    // ---- stage 2 hi terms ----
    f4_t a11 = *(const f4_t*)&sh_bias[0 + f0];
    f4_t a12 = *(const f4_t*)&sh_bias[128 + f0];
    f4_t a21 = *(const f4_t*)&sh_bias[256 + f0];
    f4_t a22 = *(const f4_t*)&sh_bias[384 + f0];
    #pragma unroll
    for (int kk = 0; kk < 4; ++kk) {
      bf8_t ohf = *(const bf8_t*)&sh_oh[roff[kk]];
      bf8_t olf = *(const bf8_t*)&sh_ol[roff[kk]];
      bf8_t o3f = *(const bf8_t*)&sh_o3[roff[kk]];
      bf8_t o3lf = *(const bf8_t*)&sh_o3l[roff[kk]];
      a11 = MFMA16(wf[4][kk], ohf, a11); a11 = MFMA16(wf[4][kk], olf, a11);
      a12 = MFMA16(wf[5][kk], ohf, a12); a12 = MFMA16(wf[5][kk], olf, a12);
      a21 = MFMA16(wf[6][kk], o3f, a21); a21 = MFMA16(wf[6][kk], o3lf, a21);
      a22 = MFMA16(wf[7][kk], o3f, a22); a22 = MFMA16(wf[7][kk], o3lf, a22);
    }
    // ---- stage 2 lo-weight terms ----
    #pragma unroll
    for (int kk = 0; kk < 4; ++kk) {
      bf8_t ohf = *(const bf8_t*)&sh_oh[roff[kk]];
      bf8_t o3f = *(const bf8_t*)&sh_o3[roff[kk]];
      a11 = MFMA16(gf0[kk], ohf, a11);
      a12 = MFMA16(gf1[kk], ohf, a12);
      a21 = MFMA16(gf2[kk], o3f, a21);
      a22 = MFMA16(gf3[kk], o3f, a22);
    }

    // ---- E2: state update + y partial + write h,c (hi+lo) ----
    f4_t xn = skxn + dfxn;
    float part = 0.f;
    f4_t hv;
    #pragma unroll
    for (int r = 0; r < 4; ++r) {
      float g = tanh_f(a11[r]) * sigm(a12[r]);
      cst[r] += g;
      float hh = tanh_f(a21[r]) * sigm(a22[r]) + cst[r];
      hv[r] = hh;
      part += xn[r] * hh;
    }
    part += __shfl_xor(part, 16);
    part += __shfl_xor(part, 32);
    if (lane < 16) sh_red[lane * 8 + w] = part;

    u16 hb[4], hlb[4], cb[4], clb[4];
    #pragma unroll
    for (int r = 0; r < 4; ++r) {
      hb[r] = f2bf(hv[r]);
      hlb[r] = f2bf_t(hv[r] - bf2f(hb[r]));
      cb[r] = f2bf(cst[r]);
      clb[r] = f2bf_t(cst[r] - bf2f(cb[r]));
    }
    pk.x = hb[0] | ((u32)hb[1] << 16); pk.y = hb[2] | ((u32)hb[3] << 16);
    *(uint2*)&sh_h[widx] = pk;
    pk.x = hlb[0] | ((u32)hlb[1] << 16); pk.y = hlb[2] | ((u32)hlb[3] << 16);
    *(uint2*)&sh_hl[widx] = pk;
    pk.x = cb[0] | ((u32)cb[1] << 16); pk.y = cb[2] | ((u32)cb[3] << 16);
    *(uint2*)&sh_c[widx] = pk;
    pk.x = clb[0] | ((u32)clb[1] << 16); pk.y = clb[2] | ((u32)clb[3] << 16);
    *(uint2*)&sh_cl[widx] = pk;

    // rotate indices + prefetched table fragments
    is_cur = is_nxt; id_cur = id_nxt;
    is_nxt = n_s2;   id_nxt = n_d2;
    ih_cur = n_h1;   ia_cur = n_a1;
    skq2 = nskq2; dfq2 = ndfq2; skq3 = nskq3; dfq3 = ndfq3;
    block_sync_lds();

    // ---- Y: finalize y[:, t] (wave 0) ----
    if (w == 0 && lane < 16) {
      const f4_t p0 = *(const f4_t*)&sh_red[lane * 8];
      const f4_t p1 = *(const f4_t*)&sh_red[lane * 8 + 4];
      float sfull = ((p0[0] + p0[1]) + (p0[2] + p0[3])) + ((p1[0] + p1[1]) + (p1[2] + p1[3]));
      out[(blockIdx.x * 16 + lane) * 200 + t] = sigm(sfull);
    }
  }
}

// ---------------- launcher ----------------

extern "C" void kernel_launch(void* const* d_in, const int* in_sizes, int n_in,
                              void* d_out, int out_size, void* d_ws, size_t ws_size,
                              hipStream_t stream) {
  const int* skill  = (const int*)d_in[0];
  const int* answer = (const int*)d_in[1];
  const int* diff   = (const int*)d_in[2];
  const int* hints  = (const int*)d_in[3];
  const float* skill_emb  = (const float*)d_in[5];
  const float* answer_emb = (const float*)d_in[6];
  const float* diff_emb   = (const float*)d_in[7];
  const float* hints_emb  = (const float*)d_in[8];
  const float* Wq2 = (const float*)d_in[10];
  const float* Wk2 = (const float*)d_in[11];
  const float* Wv2 = (const float*)d_in[12];
  const float* Wq3 = (const float*)d_in[13];
  const float* Wk3 = (const float*)d_in[14];
  const float* Wv3 = (const float*)d_in[15];
  const float* fc_W  = (const float*)d_in[16];
  const float* fc_b  = (const float*)d_in[17];
  const float* fc2_W = (const float*)d_in[18];
  const float* fc2_b = (const float*)d_in[19];
  const float* f11_W = (const float*)d_in[20];
  const float* f11_b = (const float*)d_in[21];
  const float* f12_W = (const float*)d_in[22];
  const float* f12_b = (const float*)d_in[23];
  const float* f21_W = (const float*)d_in[24];
  const float* f21_b = (const float*)d_in[25];
  const float* f22_W = (const float*)d_in[26];
  const float* f22_b = (const float*)d_in[27];

  float* ws = (float*)d_ws;
  float* A2 = ws + 0;          // 128x128
  float* A3 = ws + 16384;
  float* B2 = ws + 32768;
  float* B3 = ws + 49152;
  float* WB = ws + 65536;      // 256x384
  float* BB = ws + 163840;     // 384
  float* SKt = ws + 164224;    // 1002x384
  float* DFt = ws + 548992;    // 102x384
  float* TV2 = ws + 588160;    // 12x128
  float* TV3 = ws + 589696;    // 3x128
  u16* WHI = (u16*)((char*)d_ws + 2360320);  // 256 KB
  u16* FLO = (u16*)((char*)d_ws + 2622464);  // 256 KB
  float* outp = (float*)d_out;

  k_gemm128<<<16, 256, 0, stream>>>(fc2_W,         Wq2, B2);
  k_gemm128<<<16, 256, 0, stream>>>(fc2_W,         Wk3, B3);
  k_gemm128<<<16, 256, 0, stream>>>(fc2_W + 16384, Wq2, A2);
  k_gemm128<<<16, 256, 0, stream>>>(fc2_W + 16384, Wk3, A3);
  k_wbig<<<96, 256, 0, stream>>>(fc_W, B2, B3, WB);
  k_bbig<<<2, 256, 0, stream>>>(fc_b, fc2_b, B2, B3, Wq2, Wk3, BB);
  k_skdf<<<dim3(376, 2), 256, 0, stream>>>(skill_emb, diff_emb, WB, BB, SKt, DFt);
  k_tv<<<2, 256, 0, stream>>>(hints_emb, Wv2, answer_emb, Wv3, TV2, TV3);
  P8 s;
  s.p[0] = A2; s.p[1] = A3; s.p[2] = Wq3; s.p[3] = Wk2;
  s.p[4] = f11_W; s.p[5] = f12_W; s.p[6] = f21_W; s.p[7] = f22_W;
  k_pack<<<128, 256, 0, stream>>>(s, WHI, FLO);
  k_main<<<32, 512, 0, stream>>>(skill, answer, diff, hints, SKt, DFt, TV2, TV3,
                                 WHI, FLO, f11_b, f12_b, f21_b, f22_b, outp);
}

// Round 5
// 1917.078 us; speedup vs baseline: 1.3102x; 1.3102x over previous
//
#include <hip/hip_runtime.h>
#include <stdint.h>

typedef unsigned short u16;
typedef unsigned int u32;

using bf8_t = __attribute__((ext_vector_type(8))) short;   // 8 bf16 (bit patterns)
using f4_t  = __attribute__((ext_vector_type(4))) float;

#define MFMA16(a,b,c) __builtin_amdgcn_mfma_f32_16x16x32_bf16((a),(b),(c),0,0,0)

__device__ __forceinline__ u16 f2bf(float f) {      // RNE
  union { float f; u32 u; } v; v.f = f;
  u32 u = v.u;
  u += 0x7FFFu + ((u >> 16) & 1u);
  return (u16)(u >> 16);
}
__device__ __forceinline__ u16 f2bf_t(float f) {    // truncate (lo residuals only)
  union { float f; u32 u; } v; v.f = f;
  return (u16)(v.u >> 16);
}
__device__ __forceinline__ float bf2f(u16 h) {
  union { float f; u32 u; } v; v.u = ((u32)h) << 16; return v.f;
}
__device__ __forceinline__ float sigm(float x) {
  return __builtin_amdgcn_rcpf(1.f + __expf(-x));
}
__device__ __forceinline__ float tanh_f(float x) {
  x = fminf(30.f, fmaxf(-30.f, x));
  float e = __expf(-2.f * x);
  return (1.f - e) * __builtin_amdgcn_rcpf(1.f + e);
}

// ---------------- prep kernels ----------------

__global__ void k_gemm128(const float* __restrict__ A, const float* __restrict__ B,
                          float* __restrict__ C) {
  int g = blockIdx.x * 256 + threadIdx.x;
  int row = g >> 5;
  int c0 = (g & 31) << 2;
  f4_t acc = {0.f, 0.f, 0.f, 0.f};
  for (int k = 0; k < 128; ++k) {
    float a = A[row * 128 + k];
    acc += a * *(const f4_t*)&B[k * 128 + c0];
  }
  *(f4_t*)&C[row * 128 + c0] = acc;
}

__global__ void k_wbig(const float* __restrict__ fc_W, const float* __restrict__ B2,
                       const float* __restrict__ B3, float* __restrict__ WB) {
  int g = blockIdx.x * 256 + threadIdx.x;
  int row = g / 96;
  int j0 = (g % 96) * 4;
  if (j0 < 128) {
    *(f4_t*)&WB[row * 384 + j0] = *(const f4_t*)&fc_W[row * 128 + j0];
  } else {
    const float* Bm = (j0 < 256) ? B2 : B3;
    int jj = j0 & 127;
    f4_t acc = {0.f, 0.f, 0.f, 0.f};
    for (int n = 0; n < 128; ++n)
      acc += fc_W[row * 128 + n] * *(const f4_t*)&Bm[n * 128 + jj];
    *(f4_t*)&WB[row * 384 + j0] = acc;
  }
}

__global__ void k_bbig(const float* __restrict__ fc_b, const float* __restrict__ fc2_b,
                       const float* __restrict__ B2, const float* __restrict__ B3,
                       const float* __restrict__ Wq2, const float* __restrict__ Wk3,
                       float* __restrict__ bb) {
  int j = blockIdx.x * 256 + threadIdx.x;
  if (j >= 384) return;
  if (j < 128) { bb[j] = fc_b[j]; return; }
  const float* Bm = (j < 256) ? B2 : B3;
  const float* Wm = (j < 256) ? Wq2 : Wk3;
  int jj = j & 127;
  float acc = 0.f;
  for (int n = 0; n < 128; ++n)
    acc += fc_b[n] * Bm[n * 128 + jj] + fc2_b[n] * Wm[n * 128 + jj];
  bb[j] = acc;
}

__global__ void k_skdf(const float* __restrict__ skill_emb, const float* __restrict__ diff_emb,
                       const float* __restrict__ WB, const float* __restrict__ bb,
                       float* __restrict__ SK, float* __restrict__ DF) {
  int g = blockIdx.x * 256 + threadIdx.x;
  int row = g / 96, j0 = (g % 96) * 4;
  if (blockIdx.y == 0) {
    if (row >= 1002) return;
    f4_t acc = {0.f, 0.f, 0.f, 0.f};
    for (int d = 0; d < 128; ++d)
      acc += skill_emb[row * 128 + d] * *(const f4_t*)&WB[d * 384 + j0];
    *(f4_t*)&SK[row * 384 + j0] = acc;
  } else {
    if (row >= 102) return;
    f4_t acc = *(const f4_t*)&bb[j0];
    for (int d = 0; d < 128; ++d)
      acc += diff_emb[row * 128 + d] * *(const f4_t*)&WB[(128 + d) * 384 + j0];
    *(f4_t*)&DF[row * 384 + j0] = acc;
  }
}

__global__ void k_tv(const float* __restrict__ hints_emb, const float* __restrict__ Wv2,
                     const float* __restrict__ answer_emb, const float* __restrict__ Wv3,
                     float* __restrict__ Tv2, float* __restrict__ Tv3) {
  int g = blockIdx.x * 256 + threadIdx.x;
  if (g < 384) {
    int i = g >> 5, j0 = (g & 31) << 2;
    f4_t acc = {0.f, 0.f, 0.f, 0.f};
    for (int d = 0; d < 128; ++d)
      acc += hints_emb[i * 128 + d] * *(const f4_t*)&Wv2[d * 128 + j0];
    *(f4_t*)&Tv2[i * 128 + j0] = acc;
  } else if (g < 480) {
    int g2 = g - 384;
    int i = g2 >> 5, j0 = (g2 & 31) << 2;
    f4_t acc = {0.f, 0.f, 0.f, 0.f};
    for (int d = 0; d < 128; ++d)
      acc += answer_emb[i * 128 + d] * *(const f4_t*)&Wv3[d * 128 + j0];
    *(f4_t*)&Tv3[i * 128 + j0] = acc;
  }
}

// Pack in-loop weights into per-lane MFMA A-fragment order.
// whi/flo identical layout: idx = (((m*4+kk)*8+w)*64+lane)*8
// mats m: {A2,A3,Wq3,Wk2,f11,f12,f21,f22}; whi = bf16 hi, flo = bf16 lo residual.
struct P8 { const float* p[8]; };
__global__ void k_pack(P8 s, u16* __restrict__ whi, u16* __restrict__ flo) {
  int g = blockIdx.x * 256 + threadIdx.x;   // 128*256 = 32768
  bool lo = (g >= 16384);
  int gg = g & 16383;
  int m = gg >> 11;
  int r = gg & 2047;
  int kk = r >> 9, w = (r >> 6) & 7, l = r & 63;
  const float* src = s.p[m];
  int col = w * 16 + (l & 15);
  int kbase = kk * 32 + ((l >> 4) << 3);
  u16 o[8];
  #pragma unroll
  for (int e = 0; e < 8; ++e) {
    float v = src[(kbase + e) * 128 + col];
    u16 h = f2bf(v);
    o[e] = lo ? f2bf_t(v - bf2f(h)) : h;
  }
  u16* dst = (lo ? flo : whi) + gg * 8;
  uint4 u;
  u.x = o[0] | ((u32)o[1] << 16); u.y = o[2] | ((u32)o[3] << 16);
  u.z = o[4] | ((u32)o[5] << 16); u.w = o[6] | ((u32)o[7] << 16);
  *(uint4*)dst = u;
}

// ---------------- main recurrent kernel ----------------
// 32 blocks x 512 threads; block b owns batch rows 16b..16b+15.
// Wave w owns feature cols [16w,16w+16). All weight fragments (hi+lo)
// persistent in registers/AGPRs. LDS act rows padded to 136 u16 (272 B =
// 68 dwords == 4 mod 32 banks) -> even 8-pass bank distribution for
// ds_read_b128 (the old 256 B stride aliased all rows to one bank set).
// MFMA accumulation split into 2 independent partial chains per output.

#define RSTRIDE 136

__launch_bounds__(512, 1)
__global__ void k_main(const int* __restrict__ skill, const int* __restrict__ answer,
                       const int* __restrict__ diff, const int* __restrict__ hints,
                       const float* __restrict__ SK, const float* __restrict__ DF,
                       const float* __restrict__ Tv2, const float* __restrict__ Tv3,
                       const u16* __restrict__ whi, const u16* __restrict__ flo,
                       const float* __restrict__ b11p, const float* __restrict__ b12p,
                       const float* __restrict__ b21p, const float* __restrict__ b22p,
                       float* __restrict__ out) {
  __shared__ u16 sh_h[16 * RSTRIDE], sh_hl[16 * RSTRIDE];
  __shared__ u16 sh_c[16 * RSTRIDE], sh_cl[16 * RSTRIDE];
  __shared__ u16 sh_oh[16 * RSTRIDE], sh_ol[16 * RSTRIDE];
  __shared__ u16 sh_o3[16 * RSTRIDE], sh_o3l[16 * RSTRIDE];
  __shared__ float sh_tv2[12 * 132];
  __shared__ float sh_tv3[3 * 132];
  __shared__ float sh_bias[512];
  __shared__ float sh_red[16 * 8];

  const int tid = threadIdx.x;
  const int w = tid >> 6, lane = tid & 63;
  const int row = lane & 15;
  const int fgrp = lane >> 4;
  const int f0 = w * 16 + fgrp * 4;
  const int row_g = blockIdx.x * 16 + row;
  const int r200 = row_g * 200;

  // persistent weight fragments (hi + lo)
  bf8_t wf[8][4], wl[8][4];
  #pragma unroll
  for (int m = 0; m < 8; ++m)
    #pragma unroll
    for (int kk = 0; kk < 4; ++kk) {
      int idx = (((m * 4 + kk) * 8 + w) * 64 + lane) * 8;
      wf[m][kk] = *(const bf8_t*)&whi[idx];
      wl[m][kk] = *(const bf8_t*)&flo[idx];
    }

  // LDS init
  for (int i = tid; i < 16 * RSTRIDE / 2; i += 512) {
    ((u32*)sh_h)[i] = 0u; ((u32*)sh_hl)[i] = 0u;
    ((u32*)sh_c)[i] = 0u; ((u32*)sh_cl)[i] = 0u;
  }
  for (int i = tid; i < 12 * 128; i += 512) sh_tv2[(i >> 7) * 132 + (i & 127)] = Tv2[i];
  for (int i = tid; i < 3 * 128; i += 512) sh_tv3[(i >> 7) * 132 + (i & 127)] = Tv3[i];
  if (tid < 128) {
    sh_bias[tid]       = b11p[tid];
    sh_bias[128 + tid] = b12p[tid];
    sh_bias[256 + tid] = b21p[tid];
    sh_bias[384 + tid] = b22p[tid];
  }
  if (tid < 16) out[(blockIdx.x * 16 + tid) * 200 + 199] = 0.f;  // y[:,199] = 0

  f4_t cst = {0.f, 0.f, 0.f, 0.f};   // fp32 c state

  // rolling index prefetch
  int is_cur = skill[r200],     id_cur = diff[r200];
  int is_nxt = skill[r200 + 1], id_nxt = diff[r200 + 1];
  int ih_cur = hints[r200],     ia_cur = answer[r200];

  // loop-invariant LDS offsets (u16 elements)
  const float inv = 0.088388347648318447f;  // 1/sqrt(128)
  const int rbase = row * RSTRIDE;
  const int widx = rbase + f0;
  int roff[4];
  #pragma unroll
  for (int kk = 0; kk < 4; ++kk) roff[kk] = rbase + kk * 32 + fgrp * 8;

  // prologue: step-0 q-table fragments
  f4_t skq2 = *(const f4_t*)&SK[is_cur * 384 + 128 + f0];
  f4_t dfq2 = *(const f4_t*)&DF[id_cur * 384 + 128 + f0];
  f4_t skq3 = *(const f4_t*)&SK[is_cur * 384 + 256 + f0];
  f4_t dfq3 = *(const f4_t*)&DF[id_cur * 384 + 256 + f0];
  __syncthreads();

  for (int t = 0; t < 199; ++t) {
    // ---- S1 top: issue all global prefetches + LDS v-gathers ----
    f4_t skxn = *(const f4_t*)&SK[is_nxt * 384 + f0];          // x_{t+1}
    f4_t dfxn = *(const f4_t*)&DF[id_nxt * 384 + f0];
    f4_t nskq2 = *(const f4_t*)&SK[is_nxt * 384 + 128 + f0];   // step t+1 q-tables
    f4_t ndfq2 = *(const f4_t*)&DF[id_nxt * 384 + 128 + f0];
    f4_t nskq3 = *(const f4_t*)&SK[is_nxt * 384 + 256 + f0];
    f4_t ndfq3 = *(const f4_t*)&DF[id_nxt * 384 + 256 + f0];
    int tn = (t + 2 < 200) ? (t + 2) : 199;
    int n_s2 = skill[r200 + tn];
    int n_d2 = diff[r200 + tn];
    int n_h1 = hints[r200 + t + 1];
    int n_a1 = answer[r200 + t + 1];
    f4_t v2 = *(const f4_t*)&sh_tv2[ih_cur * 132 + f0];
    f4_t v3 = *(const f4_t*)&sh_tv3[ia_cur * 132 + f0];

    // ---- stage 1: two independent partial chains per output ----
    f4_t q2p0 = {0.f,0.f,0.f,0.f}, q2p1 = {0.f,0.f,0.f,0.f};
    f4_t q3p0 = {0.f,0.f,0.f,0.f}, q3p1 = {0.f,0.f,0.f,0.f};
    f4_t k3p0 = {0.f,0.f,0.f,0.f}, k3p1 = {0.f,0.f,0.f,0.f};
    f4_t k2p0 = {0.f,0.f,0.f,0.f}, k2p1 = {0.f,0.f,0.f,0.f};
    #pragma unroll
    for (int kk = 0; kk < 4; ++kk) {
      bf8_t hh = *(const bf8_t*)&sh_h[roff[kk]];
      bf8_t hl = *(const bf8_t*)&sh_hl[roff[kk]];
      bf8_t ch = *(const bf8_t*)&sh_c[roff[kk]];
      bf8_t cl = *(const bf8_t*)&sh_cl[roff[kk]];
      q2p0 = MFMA16(wf[0][kk], hh, q2p0);
      q3p0 = MFMA16(wf[1][kk], hh, q3p0);
      k3p0 = MFMA16(wf[2][kk], hh, k3p0);
      k2p0 = MFMA16(wf[3][kk], ch, k2p0);
      q2p1 = MFMA16(wf[0][kk], hl, q2p1);
      q3p1 = MFMA16(wf[1][kk], hl, q3p1);
      k3p1 = MFMA16(wf[2][kk], hl, k3p1);
      k2p1 = MFMA16(wf[3][kk], cl, k2p1);
      q2p1 = MFMA16(wl[0][kk], hh, q2p1);
      q3p1 = MFMA16(wl[1][kk], hh, q3p1);
      k3p1 = MFMA16(wl[2][kk], hh, k3p1);
      k2p1 = MFMA16(wl[3][kk], ch, k2p1);
    }

    // ---- E1: gates + write out/o3 (hi+lo) to LDS ----
    u16 oh[4], ol[4], o3h[4], o3l[4];
    #pragma unroll
    for (int r = 0; r < 4; ++r) {
      float q2v = (q2p0[r] + q2p1[r]) + (skq2[r] + dfq2[r]);
      float q3v = (q3p0[r] + q3p1[r]) + (skq3[r] + dfq3[r]);
      float k2v = k2p0[r] + k2p1[r];
      float k3v = k3p0[r] + k3p1[r];
      float ov = v2[r] * sigm(q2v * k2v * inv);
      float o3v = v3[r] * sigm(q3v * k3v * inv);
      oh[r] = f2bf(ov);
      ol[r] = f2bf_t(ov - bf2f(oh[r]));
      o3h[r] = f2bf(o3v);
      o3l[r] = f2bf_t(o3v - bf2f(o3h[r]));
    }
    uint2 pk;
    pk.x = oh[0] | ((u32)oh[1] << 16); pk.y = oh[2] | ((u32)oh[3] << 16);
    *(uint2*)&sh_oh[widx] = pk;
    pk.x = ol[0] | ((u32)ol[1] << 16); pk.y = ol[2] | ((u32)ol[3] << 16);
    *(uint2*)&sh_ol[widx] = pk;
    pk.x = o3h[0] | ((u32)o3h[1] << 16); pk.y = o3h[2] | ((u32)o3h[3] << 16);
    *(uint2*)&sh_o3[widx] = pk;
    pk.x = o3l[0] | ((u32)o3l[1] << 16); pk.y = o3l[2] | ((u32)o3l[3] << 16);
    *(uint2*)&sh_o3l[widx] = pk;
    __syncthreads();

    // ---- stage 2: two independent partial chains per output ----
    f4_t b11 = {0.f,0.f,0.f,0.f}, b11q = {0.f,0.f,0.f,0.f};
    f4_t b12 = {0.f,0.f,0.f,0.f}, b12q = {0.f,0.f,0.f,0.f};
    f4_t b21 = {0.f,0.f,0.f,0.f}, b21q = {0.f,0.f,0.f,0.f};
    f4_t b22 = {0.f,0.f,0.f,0.f}, b22q = {0.f,0.f,0.f,0.f};
    #pragma unroll
    for (int kk = 0; kk < 4; ++kk) {
      bf8_t ohf = *(const bf8_t*)&sh_oh[roff[kk]];
      bf8_t olf = *(const bf8_t*)&sh_ol[roff[kk]];
      bf8_t o3f = *(const bf8_t*)&sh_o3[roff[kk]];
      bf8_t o3lf = *(const bf8_t*)&sh_o3l[roff[kk]];
      b11 = MFMA16(wf[4][kk], ohf, b11);
      b12 = MFMA16(wf[5][kk], ohf, b12);
      b21 = MFMA16(wf[6][kk], o3f, b21);
      b22 = MFMA16(wf[7][kk], o3f, b22);
      b11q = MFMA16(wf[4][kk], olf, b11q);
      b12q = MFMA16(wf[5][kk], olf, b12q);
      b21q = MFMA16(wf[6][kk], o3lf, b21q);
      b22q = MFMA16(wf[7][kk], o3lf, b22q);
      b11q = MFMA16(wl[4][kk], ohf, b11q);
      b12q = MFMA16(wl[5][kk], ohf, b12q);
      b21q = MFMA16(wl[6][kk], o3f, b21q);
      b22q = MFMA16(wl[7][kk], o3f, b22q);
    }

    // ---- E2: state update + y partial + write h,c (hi+lo) ----
    f4_t bias11 = *(const f4_t*)&sh_bias[0 + f0];
    f4_t bias12 = *(const f4_t*)&sh_bias[128 + f0];
    f4_t bias21 = *(const f4_t*)&sh_bias[256 + f0];
    f4_t bias22 = *(const f4_t*)&sh_bias[384 + f0];
    f4_t xn = skxn + dfxn;
    float part = 0.f;
    f4_t hv;
    #pragma unroll
    for (int r = 0; r < 4; ++r) {
      float a11 = (b11[r] + b11q[r]) + bias11[r];
      float a12 = (b12[r] + b12q[r]) + bias12[r];
      float a21 = (b21[r] + b21q[r]) + bias21[r];
      float a22 = (b22[r] + b22q[r]) + bias22[r];
      float g = tanh_f(a11) * sigm(a12);
      cst[r] += g;
      float hh = tanh_f(a21) * sigm(a22) + cst[r];
      hv[r] = hh;
      part += xn[r] * hh;
    }
    part += __shfl_xor(part, 16);
    part += __shfl_xor(part, 32);
    if (lane < 16) sh_red[lane * 8 + w] = part;

    u16 hb[4], hlb[4], cb[4], clb[4];
    #pragma unroll
    for (int r = 0; r < 4; ++r) {
      hb[r] = f2bf(hv[r]);
      hlb[r] = f2bf_t(hv[r] - bf2f(hb[r]));
      cb[r] = f2bf(cst[r]);
      clb[r] = f2bf_t(cst[r] - bf2f(cb[r]));
    }
    pk.x = hb[0] | ((u32)hb[1] << 16); pk.y = hb[2] | ((u32)hb[3] << 16);
    *(uint2*)&sh_h[widx] = pk;
    pk.x = hlb[0] | ((u32)hlb[1] << 16); pk.y = hlb[2] | ((u32)hlb[3] << 16);
    *(uint2*)&sh_hl[widx] = pk;
    pk.x = cb[0] | ((u32)cb[1] << 16); pk.y = cb[2] | ((u32)cb[3] << 16);
    *(uint2*)&sh_c[widx] = pk;
    pk.x = clb[0] | ((u32)clb[1] << 16); pk.y = clb[2] | ((u32)clb[3] << 16);
    *(uint2*)&sh_cl[widx] = pk;

    // rotate indices + prefetched table fragments
    is_cur = is_nxt; id_cur = id_nxt;
    is_nxt = n_s2;   id_nxt = n_d2;
    ih_cur = n_h1;   ia_cur = n_a1;
    skq2 = nskq2; dfq2 = ndfq2; skq3 = nskq3; dfq3 = ndfq3;
    __syncthreads();

    // ---- Y: finalize y[:, t] (wave 0) ----
    if (w == 0 && lane < 16) {
      const f4_t p0 = *(const f4_t*)&sh_red[lane * 8];
      const f4_t p1 = *(const f4_t*)&sh_red[lane * 8 + 4];
      float sfull = ((p0[0] + p0[1]) + (p0[2] + p0[3])) + ((p1[0] + p1[1]) + (p1[2] + p1[3]));
      out[(blockIdx.x * 16 + lane) * 200 + t] = sigm(sfull);
    }
  }
}

// ---------------- launcher ----------------

extern "C" void kernel_launch(void* const* d_in, const int* in_sizes, int n_in,
                              void* d_out, int out_size, void* d_ws, size_t ws_size,
                              hipStream_t stream) {
  const int* skill  = (const int*)d_in[0];
  const int* answer = (const int*)d_in[1];
  const int* diff   = (const int*)d_in[2];
  const int* hints  = (const int*)d_in[3];
  const float* skill_emb  = (const float*)d_in[5];
  const float* answer_emb = (const float*)d_in[6];
  const float* diff_emb   = (const float*)d_in[7];
  const float* hints_emb  = (const float*)d_in[8];
  const float* Wq2 = (const float*)d_in[10];
  const float* Wk2 = (const float*)d_in[11];
  const float* Wv2 = (const float*)d_in[12];
  const float* Wq3 = (const float*)d_in[13];
  const float* Wk3 = (const float*)d_in[14];
  const float* Wv3 = (const float*)d_in[15];
  const float* fc_W  = (const float*)d_in[16];
  const float* fc_b  = (const float*)d_in[17];
  const float* fc2_W = (const float*)d_in[18];
  const float* fc2_b = (const float*)d_in[19];
  const float* f11_W = (const float*)d_in[20];
  const float* f11_b = (const float*)d_in[21];
  const float* f12_W = (const float*)d_in[22];
  const float* f12_b = (const float*)d_in[23];
  const float* f21_W = (const float*)d_in[24];
  const float* f21_b = (const float*)d_in[25];
  const float* f22_W = (const float*)d_in[26];
  const float* f22_b = (const float*)d_in[27];

  float* ws = (float*)d_ws;
  float* A2 = ws + 0;          // 128x128
  float* A3 = ws + 16384;
  float* B2 = ws + 32768;
  float* B3 = ws + 49152;
  float* WB = ws + 65536;      // 256x384
  float* BB = ws + 163840;     // 384
  float* SKt = ws + 164224;    // 1002x384
  float* DFt = ws + 548992;    // 102x384
  float* TV2 = ws + 588160;    // 12x128
  float* TV3 = ws + 589696;    // 3x128
  u16* WHI = (u16*)((char*)d_ws + 2360320);  // 256 KB
  u16* FLO = (u16*)((char*)d_ws + 2622464);  // 256 KB
  float* outp = (float*)d_out;

  k_gemm128<<<16, 256, 0, stream>>>(fc2_W,         Wq2, B2);
  k_gemm128<<<16, 256, 0, stream>>>(fc2_W,         Wk3, B3);
  k_gemm128<<<16, 256, 0, stream>>>(fc2_W + 16384, Wq2, A2);
  k_gemm128<<<16, 256, 0, stream>>>(fc2_W + 16384, Wk3, A3);
  k_wbig<<<96, 256, 0, stream>>>(fc_W, B2, B3, WB);
  k_bbig<<<2, 256, 0, stream>>>(fc_b, fc2_b, B2, B3, Wq2, Wk3, BB);
  k_skdf<<<dim3(376, 2), 256, 0, stream>>>(skill_emb, diff_emb, WB, BB, SKt, DFt);
  k_tv<<<2, 256, 0, stream>>>(hints_emb, Wv2, answer_emb, Wv3, TV2, TV3);
  P8 s;
  s.p[0] = A2; s.p[1] = A3; s.p[2] = Wq3; s.p[3] = Wk2;
  s.p[4] = f11_W; s.p[5] = f12_W; s.p[6] = f21_W; s.p[7] = f22_W;
  k_pack<<<128, 256, 0, stream>>>(s, WHI, FLO);
  k_main<<<32, 512, 0, stream>>>(skill, answer, diff, hints, SKt, DFt, TV2, TV3,
                                 WHI, FLO, f11_b, f12_b, f21_b, f22_b, outp);
}

// Round 8
// 1727.230 us; speedup vs baseline: 1.4543x; 1.1099x over previous
//
#include <hip/hip_runtime.h>
#include <stdint.h>

typedef unsigned short u16;
typedef unsigned int u32;
typedef unsigned long long u64;

using bf8_t = __attribute__((ext_vector_type(8))) short;   // 8 bf16 (bit patterns)
using f4_t  = __attribute__((ext_vector_type(4))) float;

#define MFMA16(a,b,c) __builtin_amdgcn_mfma_f32_16x16x32_bf16((a),(b),(c),0,0,0)
#define MFMAF8(a,b,c) __builtin_amdgcn_mfma_f32_16x16x32_fp8_fp8((a),(b),(c),0,0,0)

#define LO_SCALE 512.0f
#define LO_INV   0.001953125f   // 1/512

__device__ __forceinline__ u16 f2bf(float f) {      // RNE
  union { float f; u32 u; } v; v.f = f;
  u32 u = v.u;
  u += 0x7FFFu + ((u >> 16) & 1u);
  return (u16)(u >> 16);
}
__device__ __forceinline__ u16 f2bf_t(float f) {    // truncate (lo residuals)
  union { float f; u32 u; } v; v.f = f;
  return (u16)(v.u >> 16);
}
__device__ __forceinline__ float bf2f(u16 h) {
  union { float f; u32 u; } v; v.u = ((u32)h) << 16; return v.f;
}
__device__ __forceinline__ float sigm(float x) {
  return __builtin_amdgcn_rcpf(1.f + __expf(-x));
}
__device__ __forceinline__ float tanh_f(float x) {
  x = fminf(30.f, fmaxf(-30.f, x));
  float e = __expf(-2.f * x);
  return (1.f - e) * __builtin_amdgcn_rcpf(1.f + e);
}
__device__ __forceinline__ float u2f(u32 u) {
  union { u32 u; float f; } v; v.u = u; return v.f;
}
// 8 bf16 (one MFMA B-frag) -> 8 fp8 e4m3, same element order (byte i = elem i)
__device__ __forceinline__ long bf16x8_to_fp8(bf8_t x) {
  union { bf8_t v; u32 u[4]; } p; p.v = x;
  u32 lo = 0, hi = 0;
  lo = __builtin_amdgcn_cvt_pk_fp8_f32(u2f(p.u[0] << 16), u2f(p.u[0] & 0xFFFF0000u), (int)lo, false);
  lo = __builtin_amdgcn_cvt_pk_fp8_f32(u2f(p.u[1] << 16), u2f(p.u[1] & 0xFFFF0000u), (int)lo, true);
  hi = __builtin_amdgcn_cvt_pk_fp8_f32(u2f(p.u[2] << 16), u2f(p.u[2] & 0xFFFF0000u), (int)hi, false);
  hi = __builtin_amdgcn_cvt_pk_fp8_f32(u2f(p.u[3] << 16), u2f(p.u[3] & 0xFFFF0000u), (int)hi, true);
  return (long)(((u64)hi << 32) | (u64)lo);
}

// ---------------- prep kernels ----------------

__global__ void k_gemm128(const float* __restrict__ A, const float* __restrict__ B,
                          float* __restrict__ C) {
  int g = blockIdx.x * 256 + threadIdx.x;
  int row = g >> 5;
  int c0 = (g & 31) << 2;
  f4_t acc = {0.f, 0.f, 0.f, 0.f};
  for (int k = 0; k < 128; ++k) {
    float a = A[row * 128 + k];
    acc += a * *(const f4_t*)&B[k * 128 + c0];
  }
  *(f4_t*)&C[row * 128 + c0] = acc;
}

__global__ void k_wbig(const float* __restrict__ fc_W, const float* __restrict__ B2,
                       const float* __restrict__ B3, float* __restrict__ WB) {
  int g = blockIdx.x * 256 + threadIdx.x;
  int row = g / 96;
  int j0 = (g % 96) * 4;
  if (j0 < 128) {
    *(f4_t*)&WB[row * 384 + j0] = *(const f4_t*)&fc_W[row * 128 + j0];
  } else {
    const float* Bm = (j0 < 256) ? B2 : B3;
    int jj = j0 & 127;
    f4_t acc = {0.f, 0.f, 0.f, 0.f};
    for (int n = 0; n < 128; ++n)
      acc += fc_W[row * 128 + n] * *(const f4_t*)&Bm[n * 128 + jj];
    *(f4_t*)&WB[row * 384 + j0] = acc;
  }
}

__global__ void k_bbig(const float* __restrict__ fc_b, const float* __restrict__ fc2_b,
                       const float* __restrict__ B2, const float* __restrict__ B3,
                       const float* __restrict__ Wq2, const float* __restrict__ Wk3,
                       float* __restrict__ bb) {
  int j = blockIdx.x * 256 + threadIdx.x;
  if (j >= 384) return;
  if (j < 128) { bb[j] = fc_b[j]; return; }
  const float* Bm = (j < 256) ? B2 : B3;
  const float* Wm = (j < 256) ? Wq2 : Wk3;
  int jj = j & 127;
  float acc = 0.f;
  for (int n = 0; n < 128; ++n)
    acc += fc_b[n] * Bm[n * 128 + jj] + fc2_b[n] * Wm[n * 128 + jj];
  bb[j] = acc;
}

__global__ void k_skdf(const float* __restrict__ skill_emb, const float* __restrict__ diff_emb,
                       const float* __restrict__ WB, const float* __restrict__ bb,
                       float* __restrict__ SK, float* __restrict__ DF) {
  int g = blockIdx.x * 256 + threadIdx.x;
  int row = g / 96, j0 = (g % 96) * 4;
  if (blockIdx.y == 0) {
    if (row >= 1002) return;
    f4_t acc = {0.f, 0.f, 0.f, 0.f};
    for (int d = 0; d < 128; ++d)
      acc += skill_emb[row * 128 + d] * *(const f4_t*)&WB[d * 384 + j0];
    *(f4_t*)&SK[row * 384 + j0] = acc;
  } else {
    if (row >= 102) return;
    f4_t acc = *(const f4_t*)&bb[j0];
    for (int d = 0; d < 128; ++d)
      acc += diff_emb[row * 128 + d] * *(const f4_t*)&WB[(128 + d) * 384 + j0];
    *(f4_t*)&DF[row * 384 + j0] = acc;
  }
}

__global__ void k_tv(const float* __restrict__ hints_emb, const float* __restrict__ Wv2,
                     const float* __restrict__ answer_emb, const float* __restrict__ Wv3,
                     float* __restrict__ Tv2, float* __restrict__ Tv3) {
  int g = blockIdx.x * 256 + threadIdx.x;
  if (g < 384) {
    int i = g >> 5, j0 = (g & 31) << 2;
    f4_t acc = {0.f, 0.f, 0.f, 0.f};
    for (int d = 0; d < 128; ++d)
      acc += hints_emb[i * 128 + d] * *(const f4_t*)&Wv2[d * 128 + j0];
    *(f4_t*)&Tv2[i * 128 + j0] = acc;
  } else if (g < 480) {
    int g2 = g - 384;
    int i = g2 >> 5, j0 = (g2 & 31) << 2;
    f4_t acc = {0.f, 0.f, 0.f, 0.f};
    for (int d = 0; d < 128; ++d)
      acc += answer_emb[i * 128 + d] * *(const f4_t*)&Wv3[d * 128 + j0];
    *(f4_t*)&Tv3[i * 128 + j0] = acc;
  }
}

// Pack in-loop weights. 4-wave layout: wave w owns cols [32w,32w+32) as 2 tiles.
// frag flat index f = m*2048 + ct*1024 + kk*256 + w*64 + lane
// whi: bf16 hi (8 u16/frag). wl8: fp8 e4m3 of (residual * 512) (8 B/frag).
struct P8 { const float* p[8]; };
__global__ void k_pack(P8 s, u16* __restrict__ whi, unsigned char* __restrict__ wl8) {
  int g = blockIdx.x * 256 + threadIdx.x;   // 128*256 = 32768
  bool lo = (g >= 16384);
  int gg = g & 16383;
  int m = gg >> 11;
  int r = gg & 2047;
  int ct = (r >> 10) & 1, kk = (r >> 8) & 3, wv = (r >> 6) & 3, l = r & 63;
  const float* src = s.p[m];
  int col = wv * 32 + ct * 16 + (l & 15);
  int kbase = kk * 32 + ((l >> 4) << 3);
  if (!lo) {
    u16 o[8];
    #pragma unroll
    for (int e = 0; e < 8; ++e) o[e] = f2bf(src[(kbase + e) * 128 + col]);
    uint4 u;
    u.x = o[0] | ((u32)o[1] << 16); u.y = o[2] | ((u32)o[3] << 16);
    u.z = o[4] | ((u32)o[5] << 16); u.w = o[6] | ((u32)o[7] << 16);
    *(uint4*)(whi + gg * 8) = u;
  } else {
    float lv[8];
    #pragma unroll
    for (int e = 0; e < 8; ++e) {
      float v = src[(kbase + e) * 128 + col];
      lv[e] = (v - bf2f(f2bf(v))) * LO_SCALE;
    }
    u32 plo = 0, phi = 0;
    plo = __builtin_amdgcn_cvt_pk_fp8_f32(lv[0], lv[1], (int)plo, false);
    plo = __builtin_amdgcn_cvt_pk_fp8_f32(lv[2], lv[3], (int)plo, true);
    phi = __builtin_amdgcn_cvt_pk_fp8_f32(lv[4], lv[5], (int)phi, false);
    phi = __builtin_amdgcn_cvt_pk_fp8_f32(lv[6], lv[7], (int)phi, true);
    *(u64*)(wl8 + (size_t)gg * 8) = ((u64)phi << 32) | (u64)plo;
  }
}

// ---------------- main recurrent kernel ----------------
// 32 blocks x 256 threads (4 waves, 1 wave/SIMD -> 512-reg budget).
// Block owns 16 batch rows; wave w owns feature cols [32w,32w+32) (2 tiles).
// Weights fully register-resident: bf16 hi (256 VGPR) + fp8 e4m3 lo*512 (128).
// 3-term product: w_hi*a_hi + w_hi*a_lo (bf16 MFMA) + (w_lo*512)*a_hi (fp8
// MFMA, separate accumulator, combined * 1/512). Acts hi+lo bf16 in LDS,
// rows padded to 136. tv/bias/table reads via global (L1/L2) to off-load
// the per-CU LDS unit.

#define RSTRIDE 136

__launch_bounds__(256, 1)
__global__ void k_main(const int* __restrict__ skill, const int* __restrict__ answer,
                       const int* __restrict__ diff, const int* __restrict__ hints,
                       const float* __restrict__ SK, const float* __restrict__ DF,
                       const float* __restrict__ Tv2, const float* __restrict__ Tv3,
                       const u16* __restrict__ whi, const unsigned char* __restrict__ wl8,
                       const float* __restrict__ b11p, const float* __restrict__ b12p,
                       const float* __restrict__ b21p, const float* __restrict__ b22p,
                       float* __restrict__ out) {
  __shared__ u16 sh_h[16 * RSTRIDE], sh_hl[16 * RSTRIDE];
  __shared__ u16 sh_c[16 * RSTRIDE], sh_cl[16 * RSTRIDE];
  __shared__ u16 sh_oh[16 * RSTRIDE], sh_ol[16 * RSTRIDE];
  __shared__ u16 sh_o3[16 * RSTRIDE], sh_o3l[16 * RSTRIDE];
  __shared__ float sh_red[64];

  const int tid = threadIdx.x;
  const int w = tid >> 6, lane = tid & 63;
  const int row = lane & 15;
  const int fgrp = lane >> 4;
  const int f0a = w * 32 + fgrp * 4;        // tile 0
  const int f0b = f0a + 16;                 // tile 1
  const int row_g = blockIdx.x * 16 + row;
  const int r200 = row_g * 200;

  // -------- persistent weights (hi bf16 + lo fp8) --------
  bf8_t WH[8][2][4];
  long  WL[8][2][4];
  {
    const int base = w * 64 + lane;
    #pragma unroll
    for (int m = 0; m < 8; ++m)
      #pragma unroll
      for (int ct = 0; ct < 2; ++ct)
        #pragma unroll
        for (int kk = 0; kk < 4; ++kk) {
          int f = ((m * 2 + ct) * 4 + kk) * 256 + base;
          WH[m][ct][kk] = *(const bf8_t*)&whi[(size_t)f * 8];
          WL[m][ct][kk] = *(const long*)&wl8[(size_t)f * 8];
        }
  }

  // LDS init (h,c and their lo = 0)
  for (int i = tid; i < 16 * RSTRIDE / 2; i += 256) {
    ((u32*)sh_h)[i] = 0u; ((u32*)sh_hl)[i] = 0u;
    ((u32*)sh_c)[i] = 0u; ((u32*)sh_cl)[i] = 0u;
  }
  if (tid < 16) out[(blockIdx.x * 16 + tid) * 200 + 199] = 0.f;  // y[:,199]=0

  f4_t cstA = {0.f, 0.f, 0.f, 0.f}, cstB = {0.f, 0.f, 0.f, 0.f};

  int is_cur = skill[r200], id_cur = diff[r200];
  int ih_cur = hints[r200], ia_cur = answer[r200];

  const float inv = 0.088388347648318447f;  // 1/sqrt(128)
  const int rbase = row * RSTRIDE;
  const int widxA = rbase + f0a;
  const int widxB = rbase + f0b;
  int roff[4];
  #pragma unroll
  for (int kk = 0; kk < 4; ++kk) roff[kk] = rbase + kk * 32 + fgrp * 8;

  __syncthreads();

  for (int t = 0; t < 199; ++t) {
    // ---- S1 top: global loads (L1/L2), q-tables summed immediately ----
    f4_t v2A = *(const f4_t*)&Tv2[ih_cur * 128 + f0a];
    f4_t v2B = *(const f4_t*)&Tv2[ih_cur * 128 + f0b];
    f4_t v3A = *(const f4_t*)&Tv3[ia_cur * 128 + f0a];
    f4_t v3B = *(const f4_t*)&Tv3[ia_cur * 128 + f0b];
    f4_t q2bA = *(const f4_t*)&SK[is_cur * 384 + 128 + f0a]
              + *(const f4_t*)&DF[id_cur * 384 + 128 + f0a];
    f4_t q2bB = *(const f4_t*)&SK[is_cur * 384 + 128 + f0b]
              + *(const f4_t*)&DF[id_cur * 384 + 128 + f0b];
    f4_t q3bA = *(const f4_t*)&SK[is_cur * 384 + 256 + f0a]
              + *(const f4_t*)&DF[id_cur * 384 + 256 + f0a];
    f4_t q3bB = *(const f4_t*)&SK[is_cur * 384 + 256 + f0b]
              + *(const f4_t*)&DF[id_cur * 384 + 256 + f0b];
    int n_s = skill[r200 + t + 1];
    int n_d = diff[r200 + t + 1];
    int n_h = hints[r200 + t + 1];
    int n_a = answer[r200 + t + 1];

    // ---- stage 1 MFMAs (hi into main acc, fp8 lo into separate acc) ----
    f4_t q2A = {0.f,0.f,0.f,0.f}, q2B = {0.f,0.f,0.f,0.f};
    f4_t q3A = {0.f,0.f,0.f,0.f}, q3B = {0.f,0.f,0.f,0.f};
    f4_t k3A = {0.f,0.f,0.f,0.f}, k3B = {0.f,0.f,0.f,0.f};
    f4_t k2A = {0.f,0.f,0.f,0.f}, k2B = {0.f,0.f,0.f,0.f};
    f4_t lq2A = {0.f,0.f,0.f,0.f}, lq2B = {0.f,0.f,0.f,0.f};
    f4_t lq3A = {0.f,0.f,0.f,0.f}, lq3B = {0.f,0.f,0.f,0.f};
    f4_t lk3A = {0.f,0.f,0.f,0.f}, lk3B = {0.f,0.f,0.f,0.f};
    f4_t lk2A = {0.f,0.f,0.f,0.f}, lk2B = {0.f,0.f,0.f,0.f};
    #pragma unroll
    for (int kk = 0; kk < 4; ++kk) {
      bf8_t hh = *(const bf8_t*)&sh_h[roff[kk]];
      bf8_t hl = *(const bf8_t*)&sh_hl[roff[kk]];
      bf8_t ch = *(const bf8_t*)&sh_c[roff[kk]];
      bf8_t cl = *(const bf8_t*)&sh_cl[roff[kk]];
      long h8 = bf16x8_to_fp8(hh);
      long c8 = bf16x8_to_fp8(ch);
      q2A = MFMA16(WH[0][0][kk], hh, q2A); q2A = MFMA16(WH[0][0][kk], hl, q2A);
      lq2A = MFMAF8(WL[0][0][kk], h8, lq2A);
      q2B = MFMA16(WH[0][1][kk], hh, q2B); q2B = MFMA16(WH[0][1][kk], hl, q2B);
      lq2B = MFMAF8(WL[0][1][kk], h8, lq2B);
      q3A = MFMA16(WH[1][0][kk], hh, q3A); q3A = MFMA16(WH[1][0][kk], hl, q3A);
      lq3A = MFMAF8(WL[1][0][kk], h8, lq3A);
      q3B = MFMA16(WH[1][1][kk], hh, q3B); q3B = MFMA16(WH[1][1][kk], hl, q3B);
      lq3B = MFMAF8(WL[1][1][kk], h8, lq3B);
      k3A = MFMA16(WH[2][0][kk], hh, k3A); k3A = MFMA16(WH[2][0][kk], hl, k3A);
      lk3A = MFMAF8(WL[2][0][kk], h8, lk3A);
      k3B = MFMA16(WH[2][1][kk], hh, k3B); k3B = MFMA16(WH[2][1][kk], hl, k3B);
      lk3B = MFMAF8(WL[2][1][kk], h8, lk3B);
      k2A = MFMA16(WH[3][0][kk], ch, k2A); k2A = MFMA16(WH[3][0][kk], cl, k2A);
      lk2A = MFMAF8(WL[3][0][kk], c8, lk2A);
      k2B = MFMA16(WH[3][1][kk], ch, k2B); k2B = MFMA16(WH[3][1][kk], cl, k2B);
      lk2B = MFMAF8(WL[3][1][kk], c8, lk2B);
    }

    // ---- E1: gates + write out/o3 (hi+lo) ----
    uint2 pk;
    {
      u16 oh[4], ol[4], o3h[4], o3l[4];
      #pragma unroll
      for (int r = 0; r < 4; ++r) {
        float q2v = (q2A[r] + lq2A[r] * LO_INV) + q2bA[r];
        float q3v = (q3A[r] + lq3A[r] * LO_INV) + q3bA[r];
        float k2v = k2A[r] + lk2A[r] * LO_INV;
        float k3v = k3A[r] + lk3A[r] * LO_INV;
        float ov = v2A[r] * sigm(q2v * k2v * inv);
        float o3v = v3A[r] * sigm(q3v * k3v * inv);
        oh[r] = f2bf(ov);   ol[r] = f2bf_t(ov - bf2f(oh[r]));
        o3h[r] = f2bf(o3v); o3l[r] = f2bf_t(o3v - bf2f(o3h[r]));
      }
      pk.x = oh[0] | ((u32)oh[1] << 16); pk.y = oh[2] | ((u32)oh[3] << 16);
      *(uint2*)&sh_oh[widxA] = pk;
      pk.x = ol[0] | ((u32)ol[1] << 16); pk.y = ol[2] | ((u32)ol[3] << 16);
      *(uint2*)&sh_ol[widxA] = pk;
      pk.x = o3h[0] | ((u32)o3h[1] << 16); pk.y = o3h[2] | ((u32)o3h[3] << 16);
      *(uint2*)&sh_o3[widxA] = pk;
      pk.x = o3l[0] | ((u32)o3l[1] << 16); pk.y = o3l[2] | ((u32)o3l[3] << 16);
      *(uint2*)&sh_o3l[widxA] = pk;
    }
    {
      u16 oh[4], ol[4], o3h[4], o3l[4];
      #pragma unroll
      for (int r = 0; r < 4; ++r) {
        float q2v = (q2B[r] + lq2B[r] * LO_INV) + q2bB[r];
        float q3v = (q3B[r] + lq3B[r] * LO_INV) + q3bB[r];
        float k2v = k2B[r] + lk2B[r] * LO_INV;
        float k3v = k3B[r] + lk3B[r] * LO_INV;
        float ov = v2B[r] * sigm(q2v * k2v * inv);
        float o3v = v3B[r] * sigm(q3v * k3v * inv);
        oh[r] = f2bf(ov);   ol[r] = f2bf_t(ov - bf2f(oh[r]));
        o3h[r] = f2bf(o3v); o3l[r] = f2bf_t(o3v - bf2f(o3h[r]));
      }
      pk.x = oh[0] | ((u32)oh[1] << 16); pk.y = oh[2] | ((u32)oh[3] << 16);
      *(uint2*)&sh_oh[widxB] = pk;
      pk.x = ol[0] | ((u32)ol[1] << 16); pk.y = ol[2] | ((u32)ol[3] << 16);
      *(uint2*)&sh_ol[widxB] = pk;
      pk.x = o3h[0] | ((u32)o3h[1] << 16); pk.y = o3h[2] | ((u32)o3h[3] << 16);
      *(uint2*)&sh_o3[widxB] = pk;
      pk.x = o3l[0] | ((u32)o3l[1] << 16); pk.y = o3l[2] | ((u32)o3l[3] << 16);
      *(uint2*)&sh_o3l[widxB] = pk;
    }
    __syncthreads();

    // ---- S2 top: global loads: xn tables + biases ----
    f4_t xnA = *(const f4_t*)&SK[n_s * 384 + f0a] + *(const f4_t*)&DF[n_d * 384 + f0a];
    f4_t xnB = *(const f4_t*)&SK[n_s * 384 + f0b] + *(const f4_t*)&DF[n_d * 384 + f0b];
    f4_t b11A = *(const f4_t*)&b11p[f0a], b11B = *(const f4_t*)&b11p[f0b];
    f4_t b12A = *(const f4_t*)&b12p[f0a], b12B = *(const f4_t*)&b12p[f0b];
    f4_t b21A = *(const f4_t*)&b21p[f0a], b21B = *(const f4_t*)&b21p[f0b];
    f4_t b22A = *(const f4_t*)&b22p[f0a], b22B = *(const f4_t*)&b22p[f0b];

    // ---- stage 2 MFMAs ----
    f4_t a11A = {0.f,0.f,0.f,0.f}, a11B = {0.f,0.f,0.f,0.f};
    f4_t a12A = {0.f,0.f,0.f,0.f}, a12B = {0.f,0.f,0.f,0.f};
    f4_t a21A = {0.f,0.f,0.f,0.f}, a21B = {0.f,0.f,0.f,0.f};
    f4_t a22A = {0.f,0.f,0.f,0.f}, a22B = {0.f,0.f,0.f,0.f};
    f4_t l11A = {0.f,0.f,0.f,0.f}, l11B = {0.f,0.f,0.f,0.f};
    f4_t l12A = {0.f,0.f,0.f,0.f}, l12B = {0.f,0.f,0.f,0.f};
    f4_t l21A = {0.f,0.f,0.f,0.f}, l21B = {0.f,0.f,0.f,0.f};
    f4_t l22A = {0.f,0.f,0.f,0.f}, l22B = {0.f,0.f,0.f,0.f};
    #pragma unroll
    for (int kk = 0; kk < 4; ++kk) {
      bf8_t ohf = *(const bf8_t*)&sh_oh[roff[kk]];
      bf8_t olf = *(const bf8_t*)&sh_ol[roff[kk]];
      bf8_t o3f = *(const bf8_t*)&sh_o3[roff[kk]];
      bf8_t o3lf = *(const bf8_t*)&sh_o3l[roff[kk]];
      long o8 = bf16x8_to_fp8(ohf);
      long o38 = bf16x8_to_fp8(o3f);
      a11A = MFMA16(WH[4][0][kk], ohf, a11A); a11A = MFMA16(WH[4][0][kk], olf, a11A);
      l11A = MFMAF8(WL[4][0][kk], o8, l11A);
      a11B = MFMA16(WH[4][1][kk], ohf, a11B); a11B = MFMA16(WH[4][1][kk], olf, a11B);
      l11B = MFMAF8(WL[4][1][kk], o8, l11B);
      a12A = MFMA16(WH[5][0][kk], ohf, a12A); a12A = MFMA16(WH[5][0][kk], olf, a12A);
      l12A = MFMAF8(WL[5][0][kk], o8, l12A);
      a12B = MFMA16(WH[5][1][kk], ohf, a12B); a12B = MFMA16(WH[5][1][kk], olf, a12B);
      l12B = MFMAF8(WL[5][1][kk], o8, l12B);
      a21A = MFMA16(WH[6][0][kk], o3f, a21A); a21A = MFMA16(WH[6][0][kk], o3lf, a21A);
      l21A = MFMAF8(WL[6][0][kk], o38, l21A);
      a21B = MFMA16(WH[6][1][kk], o3f, a21B); a21B = MFMA16(WH[6][1][kk], o3lf, a21B);
      l21B = MFMAF8(WL[6][1][kk], o38, l21B);
      a22A = MFMA16(WH[7][0][kk], o3f, a22A); a22A = MFMA16(WH[7][0][kk], o3lf, a22A);
      l22A = MFMAF8(WL[7][0][kk], o38, l22A);
      a22B = MFMA16(WH[7][1][kk], o3f, a22B); a22B = MFMA16(WH[7][1][kk], o3lf, a22B);
      l22B = MFMAF8(WL[7][1][kk], o38, l22B);
    }

    // ---- E2: state update + y partial + write h,c (hi+lo) ----
    float part = 0.f;
    f4_t hvA, hvB;
    #pragma unroll
    for (int r = 0; r < 4; ++r) {
      float a11 = (a11A[r] + l11A[r] * LO_INV) + b11A[r];
      float a12 = (a12A[r] + l12A[r] * LO_INV) + b12A[r];
      float a21 = (a21A[r] + l21A[r] * LO_INV) + b21A[r];
      float a22 = (a22A[r] + l22A[r] * LO_INV) + b22A[r];
      float g = tanh_f(a11) * sigm(a12);
      cstA[r] += g;
      float hh = tanh_f(a21) * sigm(a22) + cstA[r];
      hvA[r] = hh;
      part += xnA[r] * hh;
    }
    #pragma unroll
    for (int r = 0; r < 4; ++r) {
      float a11 = (a11B[r] + l11B[r] * LO_INV) + b11B[r];
      float a12 = (a12B[r] + l12B[r] * LO_INV) + b12B[r];
      float a21 = (a21B[r] + l21B[r] * LO_INV) + b21B[r];
      float a22 = (a22B[r] + l22B[r] * LO_INV) + b22B[r];
      float g = tanh_f(a11) * sigm(a12);
      cstB[r] += g;
      float hh = tanh_f(a21) * sigm(a22) + cstB[r];
      hvB[r] = hh;
      part += xnB[r] * hh;
    }
    part += __shfl_xor(part, 16);
    part += __shfl_xor(part, 32);
    if (lane < 16) sh_red[lane * 4 + w] = part;

    {
      u16 hb[4], hlb[4], cb[4], clb[4];
      #pragma unroll
      for (int r = 0; r < 4; ++r) {
        hb[r] = f2bf(hvA[r]); hlb[r] = f2bf_t(hvA[r] - bf2f(hb[r]));
        cb[r] = f2bf(cstA[r]); clb[r] = f2bf_t(cstA[r] - bf2f(cb[r]));
      }
      pk.x = hb[0] | ((u32)hb[1] << 16); pk.y = hb[2] | ((u32)hb[3] << 16);
      *(uint2*)&sh_h[widxA] = pk;
      pk.x = hlb[0] | ((u32)hlb[1] << 16); pk.y = hlb[2] | ((u32)hlb[3] << 16);
      *(uint2*)&sh_hl[widxA] = pk;
      pk.x = cb[0] | ((u32)cb[1] << 16); pk.y = cb[2] | ((u32)cb[3] << 16);
      *(uint2*)&sh_c[widxA] = pk;
      pk.x = clb[0] | ((u32)clb[1] << 16); pk.y = clb[2] | ((u32)clb[3] << 16);
      *(uint2*)&sh_cl[widxA] = pk;
    }
    {
      u16 hb[4], hlb[4], cb[4], clb[4];
      #pragma unroll
      for (int r = 0; r < 4; ++r) {
        hb[r] = f2bf(hvB[r]); hlb[r] = f2bf_t(hvB[r] - bf2f(hb[r]));
        cb[r] = f2bf(cstB[r]); clb[r] = f2bf_t(cstB[r] - bf2f(cb[r]));
      }
      pk.x = hb[0] | ((u32)hb[1] << 16); pk.y = hb[2] | ((u32)hb[3] << 16);
      *(uint2*)&sh_h[widxB] = pk;
      pk.x = hlb[0] | ((u32)hlb[1] << 16); pk.y = hlb[2] | ((u32)hlb[3] << 16);
      *(uint2*)&sh_hl[widxB] = pk;
      pk.x = cb[0] | ((u32)cb[1] << 16); pk.y = cb[2] | ((u32)cb[3] << 16);
      *(uint2*)&sh_c[widxB] = pk;
      pk.x = clb[0] | ((u32)clb[1] << 16); pk.y = clb[2] | ((u32)clb[3] << 16);
      *(uint2*)&sh_cl[widxB] = pk;
    }

    is_cur = n_s; id_cur = n_d; ih_cur = n_h; ia_cur = n_a;
    __syncthreads();

    // ---- Y: finalize y[:, t] (wave 0) ----
    if (w == 0 && lane < 16) {
      const f4_t p = *(const f4_t*)&sh_red[lane * 4];
      out[(blockIdx.x * 16 + lane) * 200 + t] = sigm((p[0] + p[1]) + (p[2] + p[3]));
    }
  }
}

// ---------------- launcher ----------------

extern "C" void kernel_launch(void* const* d_in, const int* in_sizes, int n_in,
                              void* d_out, int out_size, void* d_ws, size_t ws_size,
                              hipStream_t stream) {
  const int* skill  = (const int*)d_in[0];
  const int* answer = (const int*)d_in[1];
  const int* diff   = (const int*)d_in[2];
  const int* hints  = (const int*)d_in[3];
  const float* skill_emb  = (const float*)d_in[5];
  const float* answer_emb = (const float*)d_in[6];
  const float* diff_emb   = (const float*)d_in[7];
  const float* hints_emb  = (const float*)d_in[8];
  const float* Wq2 = (const float*)d_in[10];
  const float* Wk2 = (const float*)d_in[11];
  const float* Wv2 = (const float*)d_in[12];
  const float* Wq3 = (const float*)d_in[13];
  const float* Wk3 = (const float*)d_in[14];
  const float* Wv3 = (const float*)d_in[15];
  const float* fc_W  = (const float*)d_in[16];
  const float* fc_b  = (const float*)d_in[17];
  const float* fc2_W = (const float*)d_in[18];
  const float* fc2_b = (const float*)d_in[19];
  const float* f11_W = (const float*)d_in[20];
  const float* f11_b = (const float*)d_in[21];
  const float* f12_W = (const float*)d_in[22];
  const float* f12_b = (const float*)d_in[23];
  const float* f21_W = (const float*)d_in[24];
  const float* f21_b = (const float*)d_in[25];
  const float* f22_W = (const float*)d_in[26];
  const float* f22_b = (const float*)d_in[27];

  float* ws = (float*)d_ws;
  float* A2 = ws + 0;          // 128x128
  float* A3 = ws + 16384;
  float* B2 = ws + 32768;
  float* B3 = ws + 49152;
  float* WB = ws + 65536;      // 256x384
  float* BB = ws + 163840;     // 384
  float* SKt = ws + 164224;    // 1002x384
  float* DFt = ws + 548992;    // 102x384
  float* TV2 = ws + 588160;    // 12x128
  float* TV3 = ws + 589696;    // 3x128
  u16* WHI = (u16*)((char*)d_ws + 2360320);            // 256 KB
  unsigned char* WL8 = (unsigned char*)d_ws + 2622464; // 128 KB
  float* outp = (float*)d_out;

  k_gemm128<<<16, 256, 0, stream>>>(fc2_W,         Wq2, B2);
  k_gemm128<<<16, 256, 0, stream>>>(fc2_W,         Wk3, B3);
  k_gemm128<<<16, 256, 0, stream>>>(fc2_W + 16384, Wq2, A2);
  k_gemm128<<<16, 256, 0, stream>>>(fc2_W + 16384, Wk3, A3);
  k_wbig<<<96, 256, 0, stream>>>(fc_W, B2, B3, WB);
  k_bbig<<<2, 256, 0, stream>>>(fc_b, fc2_b, B2, B3, Wq2, Wk3, BB);
  k_skdf<<<dim3(376, 2), 256, 0, stream>>>(skill_emb, diff_emb, WB, BB, SKt, DFt);
  k_tv<<<2, 256, 0, stream>>>(hints_emb, Wv2, answer_emb, Wv3, TV2, TV3);
  P8 s;
  s.p[0] = A2; s.p[1] = A3; s.p[2] = Wq3; s.p[3] = Wk2;
  s.p[4] = f11_W; s.p[5] = f12_W; s.p[6] = f21_W; s.p[7] = f22_W;
  k_pack<<<128, 256, 0, stream>>>(s, WHI, WL8);
  k_main<<<32, 256, 0, stream>>>(skill, answer, diff, hints, SKt, DFt, TV2, TV3,
                                 WHI, WL8, f11_b, f12_b, f21_b, f22_b, outp);
}

// Round 10
// 1612.612 us; speedup vs baseline: 1.5576x; 1.0711x over previous
//
#include <hip/hip_runtime.h>
#include <stdint.h>

typedef unsigned short u16;
typedef unsigned char u8;
typedef unsigned int u32;
typedef unsigned long long u64;

using h8f  = __attribute__((ext_vector_type(8))) _Float16;  // 8 f16 (one MFMA frag)
using f4_t = __attribute__((ext_vector_type(4))) float;

#define MFMAH(a,b,c)  __builtin_amdgcn_mfma_f32_16x16x32_f16((a),(b),(c),0,0,0)
#define MFMAF8(a,b,c) __builtin_amdgcn_mfma_f32_16x16x32_fp8_fp8((a),(b),(c),0,0,0)

#define LO_SCALE 4096.0f
#define LO_INV   0.000244140625f   // 1/4096

__device__ __forceinline__ float sigm(float x) {
  return __builtin_amdgcn_rcpf(1.f + __expf(-x));
}
__device__ __forceinline__ float tanh_f(float x) {
  x = fminf(30.f, fmaxf(-30.f, x));
  float e = __expf(-2.f * x);
  return (1.f - e) * __builtin_amdgcn_rcpf(1.f + e);
}
__device__ __forceinline__ u16 f2h_bits(float f) {   // RNE f32->f16 bits
  _Float16 h = (_Float16)f;
  union { _Float16 h; u16 u; } v; v.h = h; return v.u;
}
__device__ __forceinline__ float h2f(u16 u) {
  union { _Float16 h; u16 u; } v; v.u = u; return (float)v.h;
}
// pack 4 f32 -> 2 u32 of f16 (RNE)
__device__ __forceinline__ uint2 pk4h(float a, float b, float c, float d) {
  uint2 r;
  r.x = (u32)f2h_bits(a) | ((u32)f2h_bits(b) << 16);
  r.y = (u32)f2h_bits(c) | ((u32)f2h_bits(d) << 16);
  return r;
}
// pack 4 f32 -> 1 u32 of fp8 e4m3
__device__ __forceinline__ u32 pk4f8(float a, float b, float c, float d) {
  u32 r = 0;
  r = __builtin_amdgcn_cvt_pk_fp8_f32(a, b, (int)r, false);
  r = __builtin_amdgcn_cvt_pk_fp8_f32(c, d, (int)r, true);
  return r;
}

// ---------------- prep kernels ----------------

__global__ void k_gemm128(const float* __restrict__ A, const float* __restrict__ B,
                          float* __restrict__ C) {
  int g = blockIdx.x * 256 + threadIdx.x;
  int row = g >> 5;
  int c0 = (g & 31) << 2;
  f4_t acc = {0.f, 0.f, 0.f, 0.f};
  for (int k = 0; k < 128; ++k) {
    float a = A[row * 128 + k];
    acc += a * *(const f4_t*)&B[k * 128 + c0];
  }
  *(f4_t*)&C[row * 128 + c0] = acc;
}

__global__ void k_wbig(const float* __restrict__ fc_W, const float* __restrict__ B2,
                       const float* __restrict__ B3, float* __restrict__ WB) {
  int g = blockIdx.x * 256 + threadIdx.x;
  int row = g / 96;
  int j0 = (g % 96) * 4;
  if (j0 < 128) {
    *(f4_t*)&WB[row * 384 + j0] = *(const f4_t*)&fc_W[row * 128 + j0];
  } else {
    const float* Bm = (j0 < 256) ? B2 : B3;
    int jj = j0 & 127;
    f4_t acc = {0.f, 0.f, 0.f, 0.f};
    for (int n = 0; n < 128; ++n)
      acc += fc_W[row * 128 + n] * *(const f4_t*)&Bm[n * 128 + jj];
    *(f4_t*)&WB[row * 384 + j0] = acc;
  }
}

__global__ void k_bbig(const float* __restrict__ fc_b, const float* __restrict__ fc2_b,
                       const float* __restrict__ B2, const float* __restrict__ B3,
                       const float* __restrict__ Wq2, const float* __restrict__ Wk3,
                       float* __restrict__ bb) {
  int j = blockIdx.x * 256 + threadIdx.x;
  if (j >= 384) return;
  if (j < 128) { bb[j] = fc_b[j]; return; }
  const float* Bm = (j < 256) ? B2 : B3;
  const float* Wm = (j < 256) ? Wq2 : Wk3;
  int jj = j & 127;
  float acc = 0.f;
  for (int n = 0; n < 128; ++n)
    acc += fc_b[n] * Bm[n * 128 + jj] + fc2_b[n] * Wm[n * 128 + jj];
  bb[j] = acc;
}

__global__ void k_skdf(const float* __restrict__ skill_emb, const float* __restrict__ diff_emb,
                       const float* __restrict__ WB, const float* __restrict__ bb,
                       float* __restrict__ SK, float* __restrict__ DF) {
  int g = blockIdx.x * 256 + threadIdx.x;
  int row = g / 96, j0 = (g % 96) * 4;
  if (blockIdx.y == 0) {
    if (row >= 1002) return;
    f4_t acc = {0.f, 0.f, 0.f, 0.f};
    for (int d = 0; d < 128; ++d)
      acc += skill_emb[row * 128 + d] * *(const f4_t*)&WB[d * 384 + j0];
    *(f4_t*)&SK[row * 384 + j0] = acc;
  } else {
    if (row >= 102) return;
    f4_t acc = *(const f4_t*)&bb[j0];
    for (int d = 0; d < 128; ++d)
      acc += diff_emb[row * 128 + d] * *(const f4_t*)&WB[(128 + d) * 384 + j0];
    *(f4_t*)&DF[row * 384 + j0] = acc;
  }
}

__global__ void k_tv(const float* __restrict__ hints_emb, const float* __restrict__ Wv2,
                     const float* __restrict__ answer_emb, const float* __restrict__ Wv3,
                     float* __restrict__ Tv2, float* __restrict__ Tv3) {
  int g = blockIdx.x * 256 + threadIdx.x;
  if (g < 384) {
    int i = g >> 5, j0 = (g & 31) << 2;
    f4_t acc = {0.f, 0.f, 0.f, 0.f};
    for (int d = 0; d < 128; ++d)
      acc += hints_emb[i * 128 + d] * *(const f4_t*)&Wv2[d * 128 + j0];
    *(f4_t*)&Tv2[i * 128 + j0] = acc;
  } else if (g < 480) {
    int g2 = g - 384;
    int i = g2 >> 5, j0 = (g2 & 31) << 2;
    f4_t acc = {0.f, 0.f, 0.f, 0.f};
    for (int d = 0; d < 128; ++d)
      acc += answer_emb[i * 128 + d] * *(const f4_t*)&Wv3[d * 128 + j0];
    *(f4_t*)&Tv3[i * 128 + j0] = acc;
  }
}

// Pack in-loop weights. 4-wave layout: wave w owns cols [32w,32w+32) as 2 tiles.
// frag flat index f = m*2048 + ct*1024 + kk*256 + w*64 + lane
// whi: f16 hi (8 u16/frag). wl8: fp8 e4m3 of ((w - f16(w)) * 4096) (8 B/frag).
struct P8 { const float* p[8]; };
__global__ void k_pack(P8 s, u16* __restrict__ whi, u8* __restrict__ wl8) {
  int g = blockIdx.x * 256 + threadIdx.x;   // 128*256 = 32768
  bool lo = (g >= 16384);
  int gg = g & 16383;
  int m = gg >> 11;
  int r = gg & 2047;
  int ct = (r >> 10) & 1, kk = (r >> 8) & 3, wv = (r >> 6) & 3, l = r & 63;
  const float* src = s.p[m];
  int col = wv * 32 + ct * 16 + (l & 15);
  int kbase = kk * 32 + ((l >> 4) << 3);
  if (!lo) {
    u16 o[8];
    #pragma unroll
    for (int e = 0; e < 8; ++e) o[e] = f2h_bits(src[(kbase + e) * 128 + col]);
    uint4 u;
    u.x = o[0] | ((u32)o[1] << 16); u.y = o[2] | ((u32)o[3] << 16);
    u.z = o[4] | ((u32)o[5] << 16); u.w = o[6] | ((u32)o[7] << 16);
    *(uint4*)(whi + gg * 8) = u;
  } else {
    float lv[8];
    #pragma unroll
    for (int e = 0; e < 8; ++e) {
      float v = src[(kbase + e) * 128 + col];
      lv[e] = (v - (float)((_Float16)v)) * LO_SCALE;
    }
    uint2 u;
    u.x = pk4f8(lv[0], lv[1], lv[2], lv[3]);
    u.y = pk4f8(lv[4], lv[5], lv[6], lv[7]);
    *(uint2*)(wl8 + (size_t)gg * 8) = u;
  }
}

// ---------------- main recurrent kernel ----------------
// 32 blocks x 256 threads (4 waves, 1 wave/SIMD -> 512-reg budget incl AGPR).
// Block owns 16 batch rows; wave w owns feature cols [32w,32w+32) (2 tiles).
// Weights resident: f16 hi (256 regs) + fp8 e4m3 (res*4096) lo (128 regs).
// Acts: f16 hi + f16 lo (eff 2^-22) + fp8 e4m3 copy, all packed at WRITE time.
// 3-term: wh*ah + wh*al (f16 MFMA, main acc) + (wl*4096)*a8 (fp8 MFMA,
// separate acc, combined * 1/4096). Rows padded to 136 elems.

#define RSTRIDE 136

__launch_bounds__(256, 1)
__global__ void k_main(const int* __restrict__ skill, const int* __restrict__ answer,
                       const int* __restrict__ diff, const int* __restrict__ hints,
                       const float* __restrict__ SK, const float* __restrict__ DF,
                       const float* __restrict__ Tv2, const float* __restrict__ Tv3,
                       const u16* __restrict__ whi, const u8* __restrict__ wl8,
                       const float* __restrict__ b11p, const float* __restrict__ b12p,
                       const float* __restrict__ b21p, const float* __restrict__ b22p,
                       float* __restrict__ out) {
  __shared__ u16 sh_h[16 * RSTRIDE], sh_c[16 * RSTRIDE];
  __shared__ u16 sh_hl[16 * RSTRIDE], sh_cl[16 * RSTRIDE];
  __shared__ u16 sh_o[16 * RSTRIDE], sh_o3[16 * RSTRIDE];
  __shared__ u16 sh_ol[16 * RSTRIDE], sh_o3l[16 * RSTRIDE];
  __shared__ u8 sh_h8[16 * RSTRIDE], sh_c8[16 * RSTRIDE];
  __shared__ u8 sh_o8[16 * RSTRIDE], sh_o38[16 * RSTRIDE];
  __shared__ float sh_red[64];

  const int tid = threadIdx.x;
  const int w = tid >> 6, lane = tid & 63;
  const int row = lane & 15;
  const int fgrp = lane >> 4;
  const int f0a = w * 32 + fgrp * 4;        // tile 0
  const int f0b = f0a + 16;                 // tile 1
  const int row_g = blockIdx.x * 16 + row;
  const int r200 = row_g * 200;

  // -------- persistent weights (hi f16 + lo fp8) --------
  h8f  WH[8][2][4];
  long WL[8][2][4];
  {
    const int base = w * 64 + lane;
    #pragma unroll
    for (int m = 0; m < 8; ++m)
      #pragma unroll
      for (int ct = 0; ct < 2; ++ct)
        #pragma unroll
        for (int kk = 0; kk < 4; ++kk) {
          int f = ((m * 2 + ct) * 4 + kk) * 256 + base;
          WH[m][ct][kk] = *(const h8f*)&whi[(size_t)f * 8];
          WL[m][ct][kk] = *(const long*)&wl8[(size_t)f * 8];
        }
  }

  // LDS init (h,c hi/lo and fp8 copies = 0)
  for (int i = tid; i < 16 * RSTRIDE / 2; i += 256) {
    ((u32*)sh_h)[i] = 0u; ((u32*)sh_c)[i] = 0u;
    ((u32*)sh_hl)[i] = 0u; ((u32*)sh_cl)[i] = 0u;
  }
  for (int i = tid; i < 16 * RSTRIDE / 4; i += 256) {
    ((u32*)sh_h8)[i] = 0u; ((u32*)sh_c8)[i] = 0u;
  }
  if (tid < 16) out[(blockIdx.x * 16 + tid) * 200 + 199] = 0.f;  // y[:,199]=0

  f4_t cstA = {0.f, 0.f, 0.f, 0.f}, cstB = {0.f, 0.f, 0.f, 0.f};

  int is_cur = skill[r200], id_cur = diff[r200];
  int ih_cur = hints[r200], ia_cur = answer[r200];

  const float inv = 0.088388347648318447f;  // 1/sqrt(128)
  const int rbase = row * RSTRIDE;
  const int widxA = rbase + f0a;
  const int widxB = rbase + f0b;
  int roff[4];
  #pragma unroll
  for (int kk = 0; kk < 4; ++kk) roff[kk] = rbase + kk * 32 + fgrp * 8;

  __syncthreads();

  for (int t = 0; t < 199; ++t) {
    // ---- S1 top: global loads (L1/L2), q-tables summed immediately ----
    f4_t v2A = *(const f4_t*)&Tv2[ih_cur * 128 + f0a];
    f4_t v2B = *(const f4_t*)&Tv2[ih_cur * 128 + f0b];
    f4_t v3A = *(const f4_t*)&Tv3[ia_cur * 128 + f0a];
    f4_t v3B = *(const f4_t*)&Tv3[ia_cur * 128 + f0b];
    f4_t q2bA = *(const f4_t*)&SK[is_cur * 384 + 128 + f0a]
              + *(const f4_t*)&DF[id_cur * 384 + 128 + f0a];
    f4_t q2bB = *(const f4_t*)&SK[is_cur * 384 + 128 + f0b]
              + *(const f4_t*)&DF[id_cur * 384 + 128 + f0b];
    f4_t q3bA = *(const f4_t*)&SK[is_cur * 384 + 256 + f0a]
              + *(const f4_t*)&DF[id_cur * 384 + 256 + f0a];
    f4_t q3bB = *(const f4_t*)&SK[is_cur * 384 + 256 + f0b]
              + *(const f4_t*)&DF[id_cur * 384 + 256 + f0b];
    int n_s = skill[r200 + t + 1];
    int n_d = diff[r200 + t + 1];
    int n_h = hints[r200 + t + 1];
    int n_a = answer[r200 + t + 1];

    // ---- stage 1 MFMAs: f16 main (hi+lo act) + fp8 lo (separate acc) ----
    f4_t q2A = {0.f,0.f,0.f,0.f}, q2B = {0.f,0.f,0.f,0.f};
    f4_t q3A = {0.f,0.f,0.f,0.f}, q3B = {0.f,0.f,0.f,0.f};
    f4_t k3A = {0.f,0.f,0.f,0.f}, k3B = {0.f,0.f,0.f,0.f};
    f4_t k2A = {0.f,0.f,0.f,0.f}, k2B = {0.f,0.f,0.f,0.f};
    f4_t lq2A = {0.f,0.f,0.f,0.f}, lq2B = {0.f,0.f,0.f,0.f};
    f4_t lq3A = {0.f,0.f,0.f,0.f}, lq3B = {0.f,0.f,0.f,0.f};
    f4_t lk3A = {0.f,0.f,0.f,0.f}, lk3B = {0.f,0.f,0.f,0.f};
    f4_t lk2A = {0.f,0.f,0.f,0.f}, lk2B = {0.f,0.f,0.f,0.f};
    #pragma unroll
    for (int kk = 0; kk < 4; ++kk) {
      h8f  hh = *(const h8f*)&sh_h[roff[kk]];
      h8f  hl = *(const h8f*)&sh_hl[roff[kk]];
      h8f  ch = *(const h8f*)&sh_c[roff[kk]];
      h8f  cl = *(const h8f*)&sh_cl[roff[kk]];
      long h8 = *(const long*)&sh_h8[roff[kk]];
      long c8 = *(const long*)&sh_c8[roff[kk]];
      q2A = MFMAH(WH[0][0][kk], hh, q2A); q2A = MFMAH(WH[0][0][kk], hl, q2A);
      lq2A = MFMAF8(WL[0][0][kk], h8, lq2A);
      q2B = MFMAH(WH[0][1][kk], hh, q2B); q2B = MFMAH(WH[0][1][kk], hl, q2B);
      lq2B = MFMAF8(WL[0][1][kk], h8, lq2B);
      q3A = MFMAH(WH[1][0][kk], hh, q3A); q3A = MFMAH(WH[1][0][kk], hl, q3A);
      lq3A = MFMAF8(WL[1][0][kk], h8, lq3A);
      q3B = MFMAH(WH[1][1][kk], hh, q3B); q3B = MFMAH(WH[1][1][kk], hl, q3B);
      lq3B = MFMAF8(WL[1][1][kk], h8, lq3B);
      k3A = MFMAH(WH[2][0][kk], hh, k3A); k3A = MFMAH(WH[2][0][kk], hl, k3A);
      lk3A = MFMAF8(WL[2][0][kk], h8, lk3A);
      k3B = MFMAH(WH[2][1][kk], hh, k3B); k3B = MFMAH(WH[2][1][kk], hl, k3B);
      lk3B = MFMAF8(WL[2][1][kk], h8, lk3B);
      k2A = MFMAH(WH[3][0][kk], ch, k2A); k2A = MFMAH(WH[3][0][kk], cl, k2A);
      lk2A = MFMAF8(WL[3][0][kk], c8, lk2A);
      k2B = MFMAH(WH[3][1][kk], ch, k2B); k2B = MFMAH(WH[3][1][kk], cl, k2B);
      lk2B = MFMAF8(WL[3][1][kk], c8, lk2B);
    }

    // ---- E1: gates + write o/o3 (f16 hi+lo + fp8 copy) ----
    {
      float ov[4], o3v[4];
      #pragma unroll
      for (int r = 0; r < 4; ++r) {
        float q2v = (q2A[r] + lq2A[r] * LO_INV) + q2bA[r];
        float q3v = (q3A[r] + lq3A[r] * LO_INV) + q3bA[r];
        float k2v = k2A[r] + lk2A[r] * LO_INV;
        float k3v = k3A[r] + lk3A[r] * LO_INV;
        ov[r]  = v2A[r] * sigm(q2v * k2v * inv);
        o3v[r] = v3A[r] * sigm(q3v * k3v * inv);
      }
      uint2 ph = pk4h(ov[0], ov[1], ov[2], ov[3]);
      *(uint2*)&sh_o[widxA] = ph;
      *(uint2*)&sh_ol[widxA] = pk4h(ov[0] - h2f((u16)ph.x), ov[1] - h2f((u16)(ph.x >> 16)),
                                    ov[2] - h2f((u16)ph.y), ov[3] - h2f((u16)(ph.y >> 16)));
      uint2 p3 = pk4h(o3v[0], o3v[1], o3v[2], o3v[3]);
      *(uint2*)&sh_o3[widxA] = p3;
      *(uint2*)&sh_o3l[widxA] = pk4h(o3v[0] - h2f((u16)p3.x), o3v[1] - h2f((u16)(p3.x >> 16)),
                                     o3v[2] - h2f((u16)p3.y), o3v[3] - h2f((u16)(p3.y >> 16)));
      *(u32*)&sh_o8[widxA]  = pk4f8(ov[0], ov[1], ov[2], ov[3]);
      *(u32*)&sh_o38[widxA] = pk4f8(o3v[0], o3v[1], o3v[2], o3v[3]);
    }
    {
      float ov[4], o3v[4];
      #pragma unroll
      for (int r = 0; r < 4; ++r) {
        float q2v = (q2B[r] + lq2B[r] * LO_INV) + q2bB[r];
        float q3v = (q3B[r] + lq3B[r] * LO_INV) + q3bB[r];
        float k2v = k2B[r] + lk2B[r] * LO_INV;
        float k3v = k3B[r] + lk3B[r] * LO_INV;
        ov[r]  = v2B[r] * sigm(q2v * k2v * inv);
        o3v[r] = v3B[r] * sigm(q3v * k3v * inv);
      }
      uint2 ph = pk4h(ov[0], ov[1], ov[2], ov[3]);
      *(uint2*)&sh_o[widxB] = ph;
      *(uint2*)&sh_ol[widxB] = pk4h(ov[0] - h2f((u16)ph.x), ov[1] - h2f((u16)(ph.x >> 16)),
                                    ov[2] - h2f((u16)ph.y), ov[3] - h2f((u16)(ph.y >> 16)));
      uint2 p3 = pk4h(o3v[0], o3v[1], o3v[2], o3v[3]);
      *(uint2*)&sh_o3[widxB] = p3;
      *(uint2*)&sh_o3l[widxB] = pk4h(o3v[0] - h2f((u16)p3.x), o3v[1] - h2f((u16)(p3.x >> 16)),
                                     o3v[2] - h2f((u16)p3.y), o3v[3] - h2f((u16)(p3.y >> 16)));
      *(u32*)&sh_o8[widxB]  = pk4f8(ov[0], ov[1], ov[2], ov[3]);
      *(u32*)&sh_o38[widxB] = pk4f8(o3v[0], o3v[1], o3v[2], o3v[3]);
    }
    __syncthreads();

    // ---- S2 top: global loads: xn tables + biases ----
    f4_t xnA = *(const f4_t*)&SK[n_s * 384 + f0a] + *(const f4_t*)&DF[n_d * 384 + f0a];
    f4_t xnB = *(const f4_t*)&SK[n_s * 384 + f0b] + *(const f4_t*)&DF[n_d * 384 + f0b];
    f4_t b11A = *(const f4_t*)&b11p[f0a], b11B = *(const f4_t*)&b11p[f0b];
    f4_t b12A = *(const f4_t*)&b12p[f0a], b12B = *(const f4_t*)&b12p[f0b];
    f4_t b21A = *(const f4_t*)&b21p[f0a], b21B = *(const f4_t*)&b21p[f0b];
    f4_t b22A = *(const f4_t*)&b22p[f0a], b22B = *(const f4_t*)&b22p[f0b];

    // ---- stage 2 MFMAs ----
    f4_t a11A = {0.f,0.f,0.f,0.f}, a11B = {0.f,0.f,0.f,0.f};
    f4_t a12A = {0.f,0.f,0.f,0.f}, a12B = {0.f,0.f,0.f,0.f};
    f4_t a21A = {0.f,0.f,0.f,0.f}, a21B = {0.f,0.f,0.f,0.f};
    f4_t a22A = {0.f,0.f,0.f,0.f}, a22B = {0.f,0.f,0.f,0.f};
    f4_t l11A = {0.f,0.f,0.f,0.f}, l11B = {0.f,0.f,0.f,0.f};
    f4_t l12A = {0.f,0.f,0.f,0.f}, l12B = {0.f,0.f,0.f,0.f};
    f4_t l21A = {0.f,0.f,0.f,0.f}, l21B = {0.f,0.f,0.f,0.f};
    f4_t l22A = {0.f,0.f,0.f,0.f}, l22B = {0.f,0.f,0.f,0.f};
    #pragma unroll
    for (int kk = 0; kk < 4; ++kk) {
      h8f  of  = *(const h8f*)&sh_o[roff[kk]];
      h8f  olf = *(const h8f*)&sh_ol[roff[kk]];
      h8f  o3f = *(const h8f*)&sh_o3[roff[kk]];
      h8f  o3lf = *(const h8f*)&sh_o3l[roff[kk]];
      long o8  = *(const long*)&sh_o8[roff[kk]];
      long o38 = *(const long*)&sh_o38[roff[kk]];
      a11A = MFMAH(WH[4][0][kk], of, a11A); a11A = MFMAH(WH[4][0][kk], olf, a11A);
      l11A = MFMAF8(WL[4][0][kk], o8, l11A);
      a11B = MFMAH(WH[4][1][kk], of, a11B); a11B = MFMAH(WH[4][1][kk], olf, a11B);
      l11B = MFMAF8(WL[4][1][kk], o8, l11B);
      a12A = MFMAH(WH[5][0][kk], of, a12A); a12A = MFMAH(WH[5][0][kk], olf, a12A);
      l12A = MFMAF8(WL[5][0][kk], o8, l12A);
      a12B = MFMAH(WH[5][1][kk], of, a12B); a12B = MFMAH(WH[5][1][kk], olf, a12B);
      l12B = MFMAF8(WL[5][1][kk], o8, l12B);
      a21A = MFMAH(WH[6][0][kk], o3f, a21A); a21A = MFMAH(WH[6][0][kk], o3lf, a21A);
      l21A = MFMAF8(WL[6][0][kk], o38, l21A);
      a21B = MFMAH(WH[6][1][kk], o3f, a21B); a21B = MFMAH(WH[6][1][kk], o3lf, a21B);
      l21B = MFMAF8(WL[6][1][kk], o38, l21B);
      a22A = MFMAH(WH[7][0][kk], o3f, a22A); a22A = MFMAH(WH[7][0][kk], o3lf, a22A);
      l22A = MFMAF8(WL[7][0][kk], o38, l22A);
      a22B = MFMAH(WH[7][1][kk], o3f, a22B); a22B = MFMAH(WH[7][1][kk], o3lf, a22B);
      l22B = MFMAF8(WL[7][1][kk], o38, l22B);
    }

    // ---- E2: state update + y partial + write h,c (f16 hi+lo + fp8 copy) ----
    float part = 0.f;
    f4_t hvA, hvB;
    #pragma unroll
    for (int r = 0; r < 4; ++r) {
      float a11 = (a11A[r] + l11A[r] * LO_INV) + b11A[r];
      float a12 = (a12A[r] + l12A[r] * LO_INV) + b12A[r];
      float a21 = (a21A[r] + l21A[r] * LO_INV) + b21A[r];
      float a22 = (a22A[r] + l22A[r] * LO_INV) + b22A[r];
      float g = tanh_f(a11) * sigm(a12);
      cstA[r] += g;
      float hh = tanh_f(a21) * sigm(a22) + cstA[r];
      hvA[r] = hh;
      part += xnA[r] * hh;
    }
    #pragma unroll
    for (int r = 0; r < 4; ++r) {
      float a11 = (a11B[r] + l11B[r] * LO_INV) + b11B[r];
      float a12 = (a12B[r] + l12B[r] * LO_INV) + b12B[r];
      float a21 = (a21B[r] + l21B[r] * LO_INV) + b21B[r];
      float a22 = (a22B[r] + l22B[r] * LO_INV) + b22B[r];
      float g = tanh_f(a11) * sigm(a12);
      cstB[r] += g;
      float hh = tanh_f(a21) * sigm(a22) + cstB[r];
      hvB[r] = hh;
      part += xnB[r] * hh;
    }
    part += __shfl_xor(part, 16);
    part += __shfl_xor(part, 32);
    if (lane < 16) sh_red[lane * 4 + w] = part;

    {
      uint2 ph = pk4h(hvA[0], hvA[1], hvA[2], hvA[3]);
      *(uint2*)&sh_h[widxA] = ph;
      *(uint2*)&sh_hl[widxA] = pk4h(hvA[0] - h2f((u16)ph.x), hvA[1] - h2f((u16)(ph.x >> 16)),
                                    hvA[2] - h2f((u16)ph.y), hvA[3] - h2f((u16)(ph.y >> 16)));
      uint2 pc = pk4h(cstA[0], cstA[1], cstA[2], cstA[3]);
      *(uint2*)&sh_c[widxA] = pc;
      *(uint2*)&sh_cl[widxA] = pk4h(cstA[0] - h2f((u16)pc.x), cstA[1] - h2f((u16)(pc.x >> 16)),
                                    cstA[2] - h2f((u16)pc.y), cstA[3] - h2f((u16)(pc.y >> 16)));
      *(u32*)&sh_h8[widxA] = pk4f8(hvA[0], hvA[1], hvA[2], hvA[3]);
      *(u32*)&sh_c8[widxA] = pk4f8(cstA[0], cstA[1], cstA[2], cstA[3]);
    }
    {
      uint2 ph = pk4h(hvB[0], hvB[1], hvB[2], hvB[3]);
      *(uint2*)&sh_h[widxB] = ph;
      *(uint2*)&sh_hl[widxB] = pk4h(hvB[0] - h2f((u16)ph.x), hvB[1] - h2f((u16)(ph.x >> 16)),
                                    hvB[2] - h2f((u16)ph.y), hvB[3] - h2f((u16)(ph.y >> 16)));
      uint2 pc = pk4h(cstB[0], cstB[1], cstB[2], cstB[3]);
      *(uint2*)&sh_c[widxB] = pc;
      *(uint2*)&sh_cl[widxB] = pk4h(cstB[0] - h2f((u16)pc.x), cstB[1] - h2f((u16)(pc.x >> 16)),
                                    cstB[2] - h2f((u16)pc.y), cstB[3] - h2f((u16)(pc.y >> 16)));
      *(u32*)&sh_h8[widxB] = pk4f8(hvB[0], hvB[1], hvB[2], hvB[3]);
      *(u32*)&sh_c8[widxB] = pk4f8(cstB[0], cstB[1], cstB[2], cstB[3]);
    }

    is_cur = n_s; id_cur = n_d; ih_cur = n_h; ia_cur = n_a;
    __syncthreads();

    // ---- Y: finalize y[:, t] (wave 0) ----
    if (w == 0 && lane < 16) {
      const f4_t p = *(const f4_t*)&sh_red[lane * 4];
      out[(blockIdx.x * 16 + lane) * 200 + t] = sigm((p[0] + p[1]) + (p[2] + p[3]));
    }
  }
}

// ---------------- launcher ----------------

extern "C" void kernel_launch(void* const* d_in, const int* in_sizes, int n_in,
                              void* d_out, int out_size, void* d_ws, size_t ws_size,
                              hipStream_t stream) {
  const int* skill  = (const int*)d_in[0];
  const int* answer = (const int*)d_in[1];
  const int* diff   = (const int*)d_in[2];
  const int* hints  = (const int*)d_in[3];
  const float* skill_emb  = (const float*)d_in[5];
  const float* answer_emb = (const float*)d_in[6];
  const float* diff_emb   = (const float*)d_in[7];
  const float* hints_emb  = (const float*)d_in[8];
  const float* Wq2 = (const float*)d_in[10];
  const float* Wk2 = (const float*)d_in[11];
  const float* Wv2 = (const float*)d_in[12];
  const float* Wq3 = (const float*)d_in[13];
  const float* Wk3 = (const float*)d_in[14];
  const float* Wv3 = (const float*)d_in[15];
  const float* fc_W  = (const float*)d_in[16];
  const float* fc_b  = (const float*)d_in[17];
  const float* fc2_W = (const float*)d_in[18];
  const float* fc2_b = (const float*)d_in[19];
  const float* f11_W = (const float*)d_in[20];
  const float* f11_b = (const float*)d_in[21];
  const float* f12_W = (const float*)d_in[22];
  const float* f12_b = (const float*)d_in[23];
  const float* f21_W = (const float*)d_in[24];
  const float* f21_b = (const float*)d_in[25];
  const float* f22_W = (const float*)d_in[26];
  const float* f22_b = (const float*)d_in[27];

  float* ws = (float*)d_ws;
  float* A2 = ws + 0;          // 128x128
  float* A3 = ws + 16384;
  float* B2 = ws + 32768;
  float* B3 = ws + 49152;
  float* WB = ws + 65536;      // 256x384
  float* BB = ws + 163840;     // 384
  float* SKt = ws + 164224;    // 1002x384
  float* DFt = ws + 548992;    // 102x384
  float* TV2 = ws + 588160;    // 12x128
  float* TV3 = ws + 589696;    // 3x128
  u16* WHI = (u16*)((char*)d_ws + 2360320);  // 256 KB
  u8* WL8 = (u8*)d_ws + 2622464;             // 128 KB
  float* outp = (float*)d_out;

  k_gemm128<<<16, 256, 0, stream>>>(fc2_W,         Wq2, B2);
  k_gemm128<<<16, 256, 0, stream>>>(fc2_W,         Wk3, B3);
  k_gemm128<<<16, 256, 0, stream>>>(fc2_W + 16384, Wq2, A2);
  k_gemm128<<<16, 256, 0, stream>>>(fc2_W + 16384, Wk3, A3);
  k_wbig<<<96, 256, 0, stream>>>(fc_W, B2, B3, WB);
  k_bbig<<<2, 256, 0, stream>>>(fc_b, fc2_b, B2, B3, Wq2, Wk3, BB);
  k_skdf<<<dim3(376, 2), 256, 0, stream>>>(skill_emb, diff_emb, WB, BB, SKt, DFt);
  k_tv<<<2, 256, 0, stream>>>(hints_emb, Wv2, answer_emb, Wv3, TV2, TV3);
  P8 s;
  s.p[0] = A2; s.p[1] = A3; s.p[2] = Wq3; s.p[3] = Wk2;
  s.p[4] = f11_W; s.p[5] = f12_W; s.p[6] = f21_W; s.p[7] = f22_W;
  k_pack<<<128, 256, 0, stream>>>(s, WHI, WL8);
  k_main<<<32, 256, 0, stream>>>(skill, answer, diff, hints, SKt, DFt, TV2, TV3,
                                 WHI, WL8, f11_b, f12_b, f21_b, f22_b, outp);
}

// Round 13
// 1245.902 us; speedup vs baseline: 2.0161x; 1.2943x over previous
//
#include <hip/hip_runtime.h>
#include <stdint.h>

typedef unsigned short u16;
typedef unsigned char u8;
typedef unsigned int u32;
typedef unsigned long long u64;

using h8f  = __attribute__((ext_vector_type(8))) _Float16;  // 8 f16 (one MFMA frag)
using f4_t = __attribute__((ext_vector_type(4))) float;
using l2_t = __attribute__((ext_vector_type(2))) long;      // 16B (two fp8 frags)

#define MFMAH(a,b,c)  __builtin_amdgcn_mfma_f32_16x16x32_f16((a),(b),(c),0,0,0)
#define MFMAF8(a,b,c) __builtin_amdgcn_mfma_f32_16x16x32_fp8_fp8((a),(b),(c),0,0,0)

#define LO_SCALE 4096.0f
#define LO_INV   0.000244140625f   // 1/4096

__device__ __forceinline__ float sigm(float x) {
  return __builtin_amdgcn_rcpf(1.f + __expf(-x));
}
__device__ __forceinline__ float tanh_f(float x) {
  x = fminf(30.f, fmaxf(-30.f, x));
  float e = __expf(-2.f * x);
  return (1.f - e) * __builtin_amdgcn_rcpf(1.f + e);
}
__device__ __forceinline__ u16 f2h_bits(float f) {   // RNE f32->f16 bits
  _Float16 h = (_Float16)f;
  union { _Float16 h; u16 u; } v; v.h = h; return v.u;
}
__device__ __forceinline__ float h2f(u16 u) {
  union { _Float16 h; u16 u; } v; v.u = u; return (float)v.h;
}
// v_cvt_pkrtz_f16_f32: 2 f32 -> 2 f16 in one instruction (RTZ; paired with an
// exact lo-residual channel so rounding mode does not matter)
__device__ __forceinline__ u32 pkrtz(float a, float b) {
  union { __attribute__((ext_vector_type(2))) __fp16 h; u32 u; } v;
  v.h = __builtin_amdgcn_cvt_pkrtz(a, b);
  return v.u;
}
// pack 4 f32 -> 1 u32 of fp8 e4m3
__device__ __forceinline__ u32 pk4f8(float a, float b, float c, float d) {
  u32 r = 0;
  r = __builtin_amdgcn_cvt_pk_fp8_f32(a, b, (int)r, false);
  r = __builtin_amdgcn_cvt_pk_fp8_f32(c, d, (int)r, true);
  return r;
}

// ---------------- prep kernels ----------------

__global__ void k_gemm128(const float* __restrict__ A, const float* __restrict__ B,
                          float* __restrict__ C) {
  int g = blockIdx.x * 256 + threadIdx.x;
  int row = g >> 5;
  int c0 = (g & 31) << 2;
  f4_t acc = {0.f, 0.f, 0.f, 0.f};
  for (int k = 0; k < 128; ++k) {
    float a = A[row * 128 + k];
    acc += a * *(const f4_t*)&B[k * 128 + c0];
  }
  *(f4_t*)&C[row * 128 + c0] = acc;
}

__global__ void k_wbig(const float* __restrict__ fc_W, const float* __restrict__ B2,
                       const float* __restrict__ B3, float* __restrict__ WB) {
  int g = blockIdx.x * 256 + threadIdx.x;
  int row = g / 96;
  int j0 = (g % 96) * 4;
  if (j0 < 128) {
    *(f4_t*)&WB[row * 384 + j0] = *(const f4_t*)&fc_W[row * 128 + j0];
  } else {
    const float* Bm = (j0 < 256) ? B2 : B3;
    int jj = j0 & 127;
    f4_t acc = {0.f, 0.f, 0.f, 0.f};
    for (int n = 0; n < 128; ++n)
      acc += fc_W[row * 128 + n] * *(const f4_t*)&Bm[n * 128 + jj];
    *(f4_t*)&WB[row * 384 + j0] = acc;
  }
}

__global__ void k_bbig(const float* __restrict__ fc_b, const float* __restrict__ fc2_b,
                       const float* __restrict__ B2, const float* __restrict__ B3,
                       const float* __restrict__ Wq2, const float* __restrict__ Wk3,
                       float* __restrict__ bb) {
  int j = blockIdx.x * 256 + threadIdx.x;
  if (j >= 384) return;
  if (j < 128) { bb[j] = fc_b[j]; return; }
  const float* Bm = (j < 256) ? B2 : B3;
  const float* Wm = (j < 256) ? Wq2 : Wk3;
  int jj = j & 127;
  float acc = 0.f;
  for (int n = 0; n < 128; ++n)
    acc += fc_b[n] * Bm[n * 128 + jj] + fc2_b[n] * Wm[n * 128 + jj];
  bb[j] = acc;
}

__global__ void k_skdf(const float* __restrict__ skill_emb, const float* __restrict__ diff_emb,
                       const float* __restrict__ WB, const float* __restrict__ bb,
                       float* __restrict__ SK, float* __restrict__ DF) {
  int g = blockIdx.x * 256 + threadIdx.x;
  int row = g / 96, j0 = (g % 96) * 4;
  if (blockIdx.y == 0) {
    if (row >= 1002) return;
    f4_t acc = {0.f, 0.f, 0.f, 0.f};
    for (int d = 0; d < 128; ++d)
      acc += skill_emb[row * 128 + d] * *(const f4_t*)&WB[d * 384 + j0];
    *(f4_t*)&SK[row * 384 + j0] = acc;
  } else {
    if (row >= 102) return;
    f4_t acc = *(const f4_t*)&bb[j0];
    for (int d = 0; d < 128; ++d)
      acc += diff_emb[row * 128 + d] * *(const f4_t*)&WB[(128 + d) * 384 + j0];
    *(f4_t*)&DF[row * 384 + j0] = acc;
  }
}

__global__ void k_tv(const float* __restrict__ hints_emb, const float* __restrict__ Wv2,
                     const float* __restrict__ answer_emb, const float* __restrict__ Wv3,
                     float* __restrict__ Tv2, float* __restrict__ Tv3) {
  int g = blockIdx.x * 256 + threadIdx.x;
  if (g < 384) {
    int i = g >> 5, j0 = (g & 31) << 2;
    f4_t acc = {0.f, 0.f, 0.f, 0.f};
    for (int d = 0; d < 128; ++d)
      acc += hints_emb[i * 128 + d] * *(const f4_t*)&Wv2[d * 128 + j0];
    *(f4_t*)&Tv2[i * 128 + j0] = acc;
  } else if (g < 480) {
    int g2 = g - 384;
    int i = g2 >> 5, j0 = (g2 & 31) << 2;
    f4_t acc = {0.f, 0.f, 0.f, 0.f};
    for (int d = 0; d < 128; ++d)
      acc += answer_emb[i * 128 + d] * *(const f4_t*)&Wv3[d * 128 + j0];
    *(f4_t*)&Tv3[i * 128 + j0] = acc;
  }
}

// Pack in-loop weights. 4-wave layout: wave w owns cols [32w,32w+32) as 2 tiles.
// frag flat index f = m*2048 + ct*1024 + kk*256 + w*64 + lane
// whi: f16 hi (8 u16/frag). wl8: fp8 e4m3 of ((w - f16(w)) * 4096) (8 B/frag).
struct P8 { const float* p[8]; };
__global__ void k_pack(P8 s, u16* __restrict__ whi, u8* __restrict__ wl8) {
  int g = blockIdx.x * 256 + threadIdx.x;   // 128*256 = 32768
  bool lo = (g >= 16384);
  int gg = g & 16383;
  int m = gg >> 11;
  int r = gg & 2047;
  int ct = (r >> 10) & 1, kk = (r >> 8) & 3, wv = (r >> 6) & 3, l = r & 63;
  const float* src = s.p[m];
  int col = wv * 32 + ct * 16 + (l & 15);
  int kbase = kk * 32 + ((l >> 4) << 3);
  if (!lo) {
    u16 o[8];
    #pragma unroll
    for (int e = 0; e < 8; ++e) o[e] = f2h_bits(src[(kbase + e) * 128 + col]);
    uint4 u;
    u.x = o[0] | ((u32)o[1] << 16); u.y = o[2] | ((u32)o[3] << 16);
    u.z = o[4] | ((u32)o[5] << 16); u.w = o[6] | ((u32)o[7] << 16);
    *(uint4*)(whi + gg * 8) = u;
  } else {
    float lv[8];
    #pragma unroll
    for (int e = 0; e < 8; ++e) {
      float v = src[(kbase + e) * 128 + col];
      lv[e] = (v - (float)((_Float16)v)) * LO_SCALE;
    }
    uint2 u;
    u.x = pk4f8(lv[0], lv[1], lv[2], lv[3]);
    u.y = pk4f8(lv[4], lv[5], lv[6], lv[7]);
    *(uint2*)(wl8 + (size_t)gg * 8) = u;
  }
}

// ---------------- main recurrent kernel ----------------
// 32 blocks x 256 threads (4 waves, 1 wave/SIMD -> 512-reg budget incl AGPR).
// Block owns 16 batch rows; wave w owns feature cols [32w,32w+32) (2 tiles).
// Weights resident: f16 hi + fp8 e4m3 (res*4096) lo (separate acc, /4096).
// ALL acts (h,c,o,o3): f16 hi + f16 lo in LDS (eff 2^-22) — the o->c->h->y
// path amplifies act error by sqrt(128) at the final logit, so o/o3 single
// f16 fails (R9/R12: 0.03). fp8 copies interleaved pairwise (h8|c8, o8|o38)
// -> one b128 read each. Rows padded (272B stride).

#define RSTRIDE 136   // u16 stride (272 B)
#define RS8 272       // byte stride for interleaved fp8 arrays

__launch_bounds__(256, 1)
__global__ void k_main(const int* __restrict__ skill, const int* __restrict__ answer,
                       const int* __restrict__ diff, const int* __restrict__ hints,
                       const float* __restrict__ SK, const float* __restrict__ DF,
                       const float* __restrict__ Tv2, const float* __restrict__ Tv3,
                       const u16* __restrict__ whi, const u8* __restrict__ wl8,
                       const float* __restrict__ b11p, const float* __restrict__ b12p,
                       const float* __restrict__ b21p, const float* __restrict__ b22p,
                       float* __restrict__ out) {
  __shared__ u16 sh_h[16 * RSTRIDE], sh_hl[16 * RSTRIDE];
  __shared__ u16 sh_c[16 * RSTRIDE], sh_cl[16 * RSTRIDE];
  __shared__ u16 sh_o[16 * RSTRIDE], sh_ol[16 * RSTRIDE];
  __shared__ u16 sh_o3[16 * RSTRIDE], sh_o3l[16 * RSTRIDE];
  __shared__ u8 sh_hc8[16 * RS8];   // [h8(8B) | c8(8B)] per 8-feat block
  __shared__ u8 sh_oo8[16 * RS8];   // [o8(8B) | o38(8B)] per 8-feat block
  __shared__ float sh_red[64];

  const int tid = threadIdx.x;
  const int w = tid >> 6, lane = tid & 63;
  const int row = lane & 15;
  const int fgrp = lane >> 4;
  const int f0a = w * 32 + fgrp * 4;        // tile 0
  const int f0b = f0a + 16;                 // tile 1
  const int row_g = blockIdx.x * 16 + row;
  const int r200 = row_g * 200;

  // -------- persistent weights (hi f16 + lo fp8) --------
  h8f  WH[8][2][4];
  long WL[8][2][4];
  {
    const int base = w * 64 + lane;
    #pragma unroll
    for (int m = 0; m < 8; ++m)
      #pragma unroll
      for (int ct = 0; ct < 2; ++ct)
        #pragma unroll
        for (int kk = 0; kk < 4; ++kk) {
          int f = ((m * 2 + ct) * 4 + kk) * 256 + base;
          WH[m][ct][kk] = *(const h8f*)&whi[(size_t)f * 8];
          WL[m][ct][kk] = *(const long*)&wl8[(size_t)f * 8];
        }
  }

  // loop-invariant biases (hoisted)
  const f4_t b11A = *(const f4_t*)&b11p[f0a], b11B = *(const f4_t*)&b11p[f0b];
  const f4_t b12A = *(const f4_t*)&b12p[f0a], b12B = *(const f4_t*)&b12p[f0b];
  const f4_t b21A = *(const f4_t*)&b21p[f0a], b21B = *(const f4_t*)&b21p[f0b];
  const f4_t b22A = *(const f4_t*)&b22p[f0a], b22B = *(const f4_t*)&b22p[f0b];

  // LDS init (h,c hi/lo and fp8 copies = 0)
  for (int i = tid; i < 16 * RSTRIDE / 2; i += 256) {
    ((u32*)sh_h)[i] = 0u; ((u32*)sh_c)[i] = 0u;
    ((u32*)sh_hl)[i] = 0u; ((u32*)sh_cl)[i] = 0u;
  }
  for (int i = tid; i < 16 * RS8 / 4; i += 256) ((u32*)sh_hc8)[i] = 0u;
  if (tid < 16) out[(blockIdx.x * 16 + tid) * 200 + 199] = 0.f;  // y[:,199]=0

  f4_t cstA = {0.f, 0.f, 0.f, 0.f}, cstB = {0.f, 0.f, 0.f, 0.f};

  int is_cur = skill[r200], id_cur = diff[r200];
  int ih_cur = hints[r200], ia_cur = answer[r200];

  const float inv = 0.088388347648318447f;  // 1/sqrt(128)
  const int rbase = row * RSTRIDE;
  const int widxA = rbase + f0a;
  const int widxB = rbase + f0b;
  int roff[4], boff[4];
  #pragma unroll
  for (int kk = 0; kk < 4; ++kk) {
    roff[kk] = rbase + kk * 32 + fgrp * 8;
    boff[kk] = row * RS8 + (kk * 4 + fgrp) * 16;
  }
  // interleaved fp8 write offsets (4-feat u32 within 8-feat block)
  const int jA = w * 4 + (fgrp >> 1);
  const int w8A = row * RS8 + jA * 16 + (fgrp & 1) * 4;
  const int w8B = w8A + 32;   // jB = jA + 2

  __syncthreads();

  for (int t = 0; t < 199; ++t) {
    // ---- S1 top: global loads (L1/L2), q-tables summed immediately ----
    f4_t v2A = *(const f4_t*)&Tv2[ih_cur * 128 + f0a];
    f4_t v2B = *(const f4_t*)&Tv2[ih_cur * 128 + f0b];
    f4_t v3A = *(const f4_t*)&Tv3[ia_cur * 128 + f0a];
    f4_t v3B = *(const f4_t*)&Tv3[ia_cur * 128 + f0b];
    f4_t q2bA = *(const f4_t*)&SK[is_cur * 384 + 128 + f0a]
              + *(const f4_t*)&DF[id_cur * 384 + 128 + f0a];
    f4_t q2bB = *(const f4_t*)&SK[is_cur * 384 + 128 + f0b]
              + *(const f4_t*)&DF[id_cur * 384 + 128 + f0b];
    f4_t q3bA = *(const f4_t*)&SK[is_cur * 384 + 256 + f0a]
              + *(const f4_t*)&DF[id_cur * 384 + 256 + f0a];
    f4_t q3bB = *(const f4_t*)&SK[is_cur * 384 + 256 + f0b]
              + *(const f4_t*)&DF[id_cur * 384 + 256 + f0b];
    int n_s = skill[r200 + t + 1];
    int n_d = diff[r200 + t + 1];
    int n_h = hints[r200 + t + 1];
    int n_a = answer[r200 + t + 1];

    // ---- stage 1 MFMAs: f16 main (hi+lo act) + fp8 lo-weight (sep acc) ----
    f4_t q2A = {0.f,0.f,0.f,0.f}, q2B = {0.f,0.f,0.f,0.f};
    f4_t q3A = {0.f,0.f,0.f,0.f}, q3B = {0.f,0.f,0.f,0.f};
    f4_t k3A = {0.f,0.f,0.f,0.f}, k3B = {0.f,0.f,0.f,0.f};
    f4_t k2A = {0.f,0.f,0.f,0.f}, k2B = {0.f,0.f,0.f,0.f};
    f4_t lq2A = {0.f,0.f,0.f,0.f}, lq2B = {0.f,0.f,0.f,0.f};
    f4_t lq3A = {0.f,0.f,0.f,0.f}, lq3B = {0.f,0.f,0.f,0.f};
    f4_t lk3A = {0.f,0.f,0.f,0.f}, lk3B = {0.f,0.f,0.f,0.f};
    f4_t lk2A = {0.f,0.f,0.f,0.f}, lk2B = {0.f,0.f,0.f,0.f};
    #pragma unroll
    for (int kk = 0; kk < 4; ++kk) {
      h8f  hh = *(const h8f*)&sh_h[roff[kk]];
      h8f  hl = *(const h8f*)&sh_hl[roff[kk]];
      h8f  ch = *(const h8f*)&sh_c[roff[kk]];
      h8f  cl = *(const h8f*)&sh_cl[roff[kk]];
      l2_t hc = *(const l2_t*)&sh_hc8[boff[kk]];
      long h8 = hc[0], c8 = hc[1];
      q2A = MFMAH(WH[0][0][kk], hh, q2A); q2A = MFMAH(WH[0][0][kk], hl, q2A);
      lq2A = MFMAF8(WL[0][0][kk], h8, lq2A);
      q2B = MFMAH(WH[0][1][kk], hh, q2B); q2B = MFMAH(WH[0][1][kk], hl, q2B);
      lq2B = MFMAF8(WL[0][1][kk], h8, lq2B);
      q3A = MFMAH(WH[1][0][kk], hh, q3A); q3A = MFMAH(WH[1][0][kk], hl, q3A);
      lq3A = MFMAF8(WL[1][0][kk], h8, lq3A);
      q3B = MFMAH(WH[1][1][kk], hh, q3B); q3B = MFMAH(WH[1][1][kk], hl, q3B);
      lq3B = MFMAF8(WL[1][1][kk], h8, lq3B);
      k3A = MFMAH(WH[2][0][kk], hh, k3A); k3A = MFMAH(WH[2][0][kk], hl, k3A);
      lk3A = MFMAF8(WL[2][0][kk], h8, lk3A);
      k3B = MFMAH(WH[2][1][kk], hh, k3B); k3B = MFMAH(WH[2][1][kk], hl, k3B);
      lk3B = MFMAF8(WL[2][1][kk], h8, lk3B);
      k2A = MFMAH(WH[3][0][kk], ch, k2A); k2A = MFMAH(WH[3][0][kk], cl, k2A);
      lk2A = MFMAF8(WL[3][0][kk], c8, lk2A);
      k2B = MFMAH(WH[3][1][kk], ch, k2B); k2B = MFMAH(WH[3][1][kk], cl, k2B);
      lk2B = MFMAF8(WL[3][1][kk], c8, lk2B);
    }

    // ---- E1: gates + write o/o3 (f16 hi+lo + interleaved fp8 copy) ----
    {
      float ov[4], o3v[4];
      #pragma unroll
      for (int r = 0; r < 4; ++r) {
        float q2v = (q2A[r] + lq2A[r] * LO_INV) + q2bA[r];
        float q3v = (q3A[r] + lq3A[r] * LO_INV) + q3bA[r];
        float k2v = k2A[r] + lk2A[r] * LO_INV;
        float k3v = k3A[r] + lk3A[r] * LO_INV;
        ov[r]  = v2A[r] * sigm(q2v * k2v * inv);
        o3v[r] = v3A[r] * sigm(q3v * k3v * inv);
      }
      uint2 ph; ph.x = pkrtz(ov[0], ov[1]); ph.y = pkrtz(ov[2], ov[3]);
      *(uint2*)&sh_o[widxA] = ph;
      uint2 pl;
      pl.x = pkrtz(ov[0] - h2f((u16)ph.x), ov[1] - h2f((u16)(ph.x >> 16)));
      pl.y = pkrtz(ov[2] - h2f((u16)ph.y), ov[3] - h2f((u16)(ph.y >> 16)));
      *(uint2*)&sh_ol[widxA] = pl;
      uint2 p3; p3.x = pkrtz(o3v[0], o3v[1]); p3.y = pkrtz(o3v[2], o3v[3]);
      *(uint2*)&sh_o3[widxA] = p3;
      uint2 p3l;
      p3l.x = pkrtz(o3v[0] - h2f((u16)p3.x), o3v[1] - h2f((u16)(p3.x >> 16)));
      p3l.y = pkrtz(o3v[2] - h2f((u16)p3.y), o3v[3] - h2f((u16)(p3.y >> 16)));
      *(uint2*)&sh_o3l[widxA] = p3l;
      *(u32*)&sh_oo8[w8A]     = pk4f8(ov[0], ov[1], ov[2], ov[3]);
      *(u32*)&sh_oo8[w8A + 8] = pk4f8(o3v[0], o3v[1], o3v[2], o3v[3]);
    }
    {
      float ov[4], o3v[4];
      #pragma unroll
      for (int r = 0; r < 4; ++r) {
        float q2v = (q2B[r] + lq2B[r] * LO_INV) + q2bB[r];
        float q3v = (q3B[r] + lq3B[r] * LO_INV) + q3bB[r];
        float k2v = k2B[r] + lk2B[r] * LO_INV;
        float k3v = k3B[r] + lk3B[r] * LO_INV;
        ov[r]  = v2B[r] * sigm(q2v * k2v * inv);
        o3v[r] = v3B[r] * sigm(q3v * k3v * inv);
      }
      uint2 ph; ph.x = pkrtz(ov[0], ov[1]); ph.y = pkrtz(ov[2], ov[3]);
      *(uint2*)&sh_o[widxB] = ph;
      uint2 pl;
      pl.x = pkrtz(ov[0] - h2f((u16)ph.x), ov[1] - h2f((u16)(ph.x >> 16)));
      pl.y = pkrtz(ov[2] - h2f((u16)ph.y), ov[3] - h2f((u16)(ph.y >> 16)));
      *(uint2*)&sh_ol[widxB] = pl;
      uint2 p3; p3.x = pkrtz(o3v[0], o3v[1]); p3.y = pkrtz(o3v[2], o3v[3]);
      *(uint2*)&sh_o3[widxB] = p3;
      uint2 p3l;
      p3l.x = pkrtz(o3v[0] - h2f((u16)p3.x), o3v[1] - h2f((u16)(p3.x >> 16)));
      p3l.y = pkrtz(o3v[2] - h2f((u16)p3.y), o3v[3] - h2f((u16)(p3.y >> 16)));
      *(uint2*)&sh_o3l[widxB] = p3l;
      *(u32*)&sh_oo8[w8B]     = pk4f8(ov[0], ov[1], ov[2], ov[3]);
      *(u32*)&sh_oo8[w8B + 8] = pk4f8(o3v[0], o3v[1], o3v[2], o3v[3]);
    }
    __syncthreads();

    // ---- S2 top: global loads: xn tables ----
    f4_t xnA = *(const f4_t*)&SK[n_s * 384 + f0a] + *(const f4_t*)&DF[n_d * 384 + f0a];
    f4_t xnB = *(const f4_t*)&SK[n_s * 384 + f0b] + *(const f4_t*)&DF[n_d * 384 + f0b];

    // ---- stage 2 MFMAs ----
    f4_t a11A = {0.f,0.f,0.f,0.f}, a11B = {0.f,0.f,0.f,0.f};
    f4_t a12A = {0.f,0.f,0.f,0.f}, a12B = {0.f,0.f,0.f,0.f};
    f4_t a21A = {0.f,0.f,0.f,0.f}, a21B = {0.f,0.f,0.f,0.f};
    f4_t a22A = {0.f,0.f,0.f,0.f}, a22B = {0.f,0.f,0.f,0.f};
    f4_t l11A = {0.f,0.f,0.f,0.f}, l11B = {0.f,0.f,0.f,0.f};
    f4_t l12A = {0.f,0.f,0.f,0.f}, l12B = {0.f,0.f,0.f,0.f};
    f4_t l21A = {0.f,0.f,0.f,0.f}, l21B = {0.f,0.f,0.f,0.f};
    f4_t l22A = {0.f,0.f,0.f,0.f}, l22B = {0.f,0.f,0.f,0.f};
    #pragma unroll
    for (int kk = 0; kk < 4; ++kk) {
      h8f  of   = *(const h8f*)&sh_o[roff[kk]];
      h8f  olf  = *(const h8f*)&sh_ol[roff[kk]];
      h8f  o3f  = *(const h8f*)&sh_o3[roff[kk]];
      h8f  o3lf = *(const h8f*)&sh_o3l[roff[kk]];
      l2_t oo = *(const l2_t*)&sh_oo8[boff[kk]];
      long o8 = oo[0], o38 = oo[1];
      a11A = MFMAH(WH[4][0][kk], of, a11A); a11A = MFMAH(WH[4][0][kk], olf, a11A);
      l11A = MFMAF8(WL[4][0][kk], o8, l11A);
      a11B = MFMAH(WH[4][1][kk], of, a11B); a11B = MFMAH(WH[4][1][kk], olf, a11B);
      l11B = MFMAF8(WL[4][1][kk], o8, l11B);
      a12A = MFMAH(WH[5][0][kk], of, a12A); a12A = MFMAH(WH[5][0][kk], olf, a12A);
      l12A = MFMAF8(WL[5][0][kk], o8, l12A);
      a12B = MFMAH(WH[5][1][kk], of, a12B); a12B = MFMAH(WH[5][1][kk], olf, a12B);
      l12B = MFMAF8(WL[5][1][kk], o8, l12B);
      a21A = MFMAH(WH[6][0][kk], o3f, a21A); a21A = MFMAH(WH[6][0][kk], o3lf, a21A);
      l21A = MFMAF8(WL[6][0][kk], o38, l21A);
      a21B = MFMAH(WH[6][1][kk], o3f, a21B); a21B = MFMAH(WH[6][1][kk], o3lf, a21B);
      l21B = MFMAF8(WL[6][1][kk], o38, l21B);
      a22A = MFMAH(WH[7][0][kk], o3f, a22A); a22A = MFMAH(WH[7][0][kk], o3lf, a22A);
      l22A = MFMAF8(WL[7][0][kk], o38, l22A);
      a22B = MFMAH(WH[7][1][kk], o3f, a22B); a22B = MFMAH(WH[7][1][kk], o3lf, a22B);
      l22B = MFMAF8(WL[7][1][kk], o38, l22B);
    }

    // ---- E2: state update + y partial + write h,c (f16 hi+lo + fp8 copy) ----
    float part = 0.f;
    f4_t hvA, hvB;
    #pragma unroll
    for (int r = 0; r < 4; ++r) {
      float a11 = (a11A[r] + l11A[r] * LO_INV) + b11A[r];
      float a12 = (a12A[r] + l12A[r] * LO_INV) + b12A[r];
      float a21 = (a21A[r] + l21A[r] * LO_INV) + b21A[r];
      float a22 = (a22A[r] + l22A[r] * LO_INV) + b22A[r];
      float g = tanh_f(a11) * sigm(a12);
      cstA[r] += g;
      float hh = tanh_f(a21) * sigm(a22) + cstA[r];
      hvA[r] = hh;
      part += xnA[r] * hh;
    }
    #pragma unroll
    for (int r = 0; r < 4; ++r) {
      float a11 = (a11B[r] + l11B[r] * LO_INV) + b11B[r];
      float a12 = (a12B[r] + l12B[r] * LO_INV) + b12B[r];
      float a21 = (a21B[r] + l21B[r] * LO_INV) + b21B[r];
      float a22 = (a22B[r] + l22B[r] * LO_INV) + b22B[r];
      float g = tanh_f(a11) * sigm(a12);
      cstB[r] += g;
      float hh = tanh_f(a21) * sigm(a22) + cstB[r];
      hvB[r] = hh;
      part += xnB[r] * hh;
    }
    part += __shfl_xor(part, 16);
    part += __shfl_xor(part, 32);
    if (lane < 16) sh_red[lane * 4 + w] = part;

    {
      uint2 ph; ph.x = pkrtz(hvA[0], hvA[1]); ph.y = pkrtz(hvA[2], hvA[3]);
      *(uint2*)&sh_h[widxA] = ph;
      uint2 pl;
      pl.x = pkrtz(hvA[0] - h2f((u16)ph.x), hvA[1] - h2f((u16)(ph.x >> 16)));
      pl.y = pkrtz(hvA[2] - h2f((u16)ph.y), hvA[3] - h2f((u16)(ph.y >> 16)));
      *(uint2*)&sh_hl[widxA] = pl;
      uint2 pc; pc.x = pkrtz(cstA[0], cstA[1]); pc.y = pkrtz(cstA[2], cstA[3]);
      *(uint2*)&sh_c[widxA] = pc;
      uint2 pcl;
      pcl.x = pkrtz(cstA[0] - h2f((u16)pc.x), cstA[1] - h2f((u16)(pc.x >> 16)));
      pcl.y = pkrtz(cstA[2] - h2f((u16)pc.y), cstA[3] - h2f((u16)(pc.y >> 16)));
      *(uint2*)&sh_cl[widxA] = pcl;
      *(u32*)&sh_hc8[w8A]     = pk4f8(hvA[0], hvA[1], hvA[2], hvA[3]);
      *(u32*)&sh_hc8[w8A + 8] = pk4f8(cstA[0], cstA[1], cstA[2], cstA[3]);
    }
    {
      uint2 ph; ph.x = pkrtz(hvB[0], hvB[1]); ph.y = pkrtz(hvB[2], hvB[3]);
      *(uint2*)&sh_h[widxB] = ph;
      uint2 pl;
      pl.x = pkrtz(hvB[0] - h2f((u16)ph.x), hvB[1] - h2f((u16)(ph.x >> 16)));
      pl.y = pkrtz(hvB[2] - h2f((u16)ph.y), hvB[3] - h2f((u16)(ph.y >> 16)));
      *(uint2*)&sh_hl[widxB] = pl;
      uint2 pc; pc.x = pkrtz(cstB[0], cstB[1]); pc.y = pkrtz(cstB[2], cstB[3]);
      *(uint2*)&sh_c[widxB] = pc;
      uint2 pcl;
      pcl.x = pkrtz(cstB[0] - h2f((u16)pc.x), cstB[1] - h2f((u16)(pc.x >> 16)));
      pcl.y = pkrtz(cstB[2] - h2f((u16)pc.y), cstB[3] - h2f((u16)(pc.y >> 16)));
      *(uint2*)&sh_cl[widxB] = pcl;
      *(u32*)&sh_hc8[w8B]     = pk4f8(hvB[0], hvB[1], hvB[2], hvB[3]);
      *(u32*)&sh_hc8[w8B + 8] = pk4f8(cstB[0], cstB[1], cstB[2], cstB[3]);
    }

    is_cur = n_s; id_cur = n_d; ih_cur = n_h; ia_cur = n_a;
    __syncthreads();

    // ---- Y: finalize y[:, t] (wave 0) ----
    if (w == 0 && lane < 16) {
      const f4_t p = *(const f4_t*)&sh_red[lane * 4];
      out[(blockIdx.x * 16 + lane) * 200 + t] = sigm((p[0] + p[1]) + (p[2] + p[3]));
    }
  }
}

// ---------------- launcher ----------------

extern "C" void kernel_launch(void* const* d_in, const int* in_sizes, int n_in,
                              void* d_out, int out_size, void* d_ws, size_t ws_size,
                              hipStream_t stream) {
  const int* skill  = (const int*)d_in[0];
  const int* answer = (const int*)d_in[1];
  const int* diff   = (const int*)d_in[2];
  const int* hints  = (const int*)d_in[3];
  const float* skill_emb  = (const float*)d_in[5];
  const float* answer_emb = (const float*)d_in[6];
  const float* diff_emb   = (const float*)d_in[7];
  const float* hints_emb  = (const float*)d_in[8];
  const float* Wq2 = (const float*)d_in[10];
  const float* Wk2 = (const float*)d_in[11];
  const float* Wv2 = (const float*)d_in[12];
  const float* Wq3 = (const float*)d_in[13];
  const float* Wk3 = (const float*)d_in[14];
  const float* Wv3 = (const float*)d_in[15];
  const float* fc_W  = (const float*)d_in[16];
  const float* fc_b  = (const float*)d_in[17];
  const float* fc2_W = (const float*)d_in[18];
  const float* fc2_b = (const float*)d_in[19];
  const float* f11_W = (const float*)d_in[20];
  const float* f11_b = (const float*)d_in[21];
  const float* f12_W = (const float*)d_in[22];
  const float* f12_b = (const float*)d_in[23];
  const float* f21_W = (const float*)d_in[24];
  const float* f21_b = (const float*)d_in[25];
  const float* f22_W = (const float*)d_in[26];
  const float* f22_b = (const float*)d_in[27];

  float* ws = (float*)d_ws;
  float* A2 = ws + 0;          // 128x128
  float* A3 = ws + 16384;
  float* B2 = ws + 32768;
  float* B3 = ws + 49152;
  float* WB = ws + 65536;      // 256x384
  float* BB = ws + 163840;     // 384
  float* SKt = ws + 164224;    // 1002x384
  float* DFt = ws + 548992;    // 102x384
  float* TV2 = ws + 588160;    // 12x128
  float* TV3 = ws + 589696;    // 3x128
  u16* WHI = (u16*)((char*)d_ws + 2360320);  // 256 KB
  u8* WL8 = (u8*)d_ws + 2622464;             // 128 KB
  float* outp = (float*)d_out;

  k_gemm128<<<16, 256, 0, stream>>>(fc2_W,         Wq2, B2);
  k_gemm128<<<16, 256, 0, stream>>>(fc2_W,         Wk3, B3);
  k_gemm128<<<16, 256, 0, stream>>>(fc2_W + 16384, Wq2, A2);
  k_gemm128<<<16, 256, 0, stream>>>(fc2_W + 16384, Wk3, A3);
  k_wbig<<<96, 256, 0, stream>>>(fc_W, B2, B3, WB);
  k_bbig<<<2, 256, 0, stream>>>(fc_b, fc2_b, B2, B3, Wq2, Wk3, BB);
  k_skdf<<<dim3(376, 2), 256, 0, stream>>>(skill_emb, diff_emb, WB, BB, SKt, DFt);
  k_tv<<<2, 256, 0, stream>>>(hints_emb, Wv2, answer_emb, Wv3, TV2, TV3);
  P8 s;
  s.p[0] = A2; s.p[1] = A3; s.p[2] = Wq3; s.p[3] = Wk2;
  s.p[4] = f11_W; s.p[5] = f12_W; s.p[6] = f21_W; s.p[7] = f22_W;
  k_pack<<<128, 256, 0, stream>>>(s, WHI, WL8);
  k_main<<<32, 256, 0, stream>>>(skill, answer, diff, hints, SKt, DFt, TV2, TV3,
                                 WHI, WL8, f11_b, f12_b, f21_b, f22_b, outp);
}

// Round 14
// 1211.569 us; speedup vs baseline: 2.0732x; 1.0283x over previous
//
#include <hip/hip_runtime.h>
#include <stdint.h>

typedef unsigned short u16;
typedef unsigned char u8;
typedef unsigned int u32;
typedef unsigned long long u64;

using h8f  = __attribute__((ext_vector_type(8))) _Float16;  // 8 f16 (one MFMA frag)
using f4_t = __attribute__((ext_vector_type(4))) float;
using l2_t = __attribute__((ext_vector_type(2))) long;      // 16B (two fp8 frags)

#define MFMAH(a,b,c)  __builtin_amdgcn_mfma_f32_16x16x32_f16((a),(b),(c),0,0,0)
#define MFMAF8(a,b,c) __builtin_amdgcn_mfma_f32_16x16x32_fp8_fp8((a),(b),(c),0,0,0)

#define LO_SCALE 4096.0f
#define LO_INV   0.000244140625f   // 1/4096

__device__ __forceinline__ float sigm(float x) {
  return __builtin_amdgcn_rcpf(1.f + __expf(-x));
}
__device__ __forceinline__ float tanh_f(float x) {
  x = fminf(30.f, fmaxf(-30.f, x));
  float e = __expf(-2.f * x);
  return (1.f - e) * __builtin_amdgcn_rcpf(1.f + e);
}
__device__ __forceinline__ u16 f2h_bits(float f) {   // RNE f32->f16 bits
  _Float16 h = (_Float16)f;
  union { _Float16 h; u16 u; } v; v.h = h; return v.u;
}
__device__ __forceinline__ float h2f(u16 u) {
  union { _Float16 h; u16 u; } v; v.u = u; return (float)v.h;
}
// v_cvt_pkrtz_f16_f32: 2 f32 -> 2 f16 (RTZ; paired with exact lo channel)
__device__ __forceinline__ u32 pkrtz(float a, float b) {
  union { __attribute__((ext_vector_type(2))) __fp16 h; u32 u; } v;
  v.h = __builtin_amdgcn_cvt_pkrtz(a, b);
  return v.u;
}
// pack 4 f32 -> 1 u32 of fp8 e4m3
__device__ __forceinline__ u32 pk4f8(float a, float b, float c, float d) {
  u32 r = 0;
  r = __builtin_amdgcn_cvt_pk_fp8_f32(a, b, (int)r, false);
  r = __builtin_amdgcn_cvt_pk_fp8_f32(c, d, (int)r, true);
  return r;
}

// ---------------- prep kernels ----------------

__global__ void k_gemm128(const float* __restrict__ A, const float* __restrict__ B,
                          float* __restrict__ C) {
  int g = blockIdx.x * 256 + threadIdx.x;
  int row = g >> 5;
  int c0 = (g & 31) << 2;
  f4_t acc = {0.f, 0.f, 0.f, 0.f};
  for (int k = 0; k < 128; ++k) {
    float a = A[row * 128 + k];
    acc += a * *(const f4_t*)&B[k * 128 + c0];
  }
  *(f4_t*)&C[row * 128 + c0] = acc;
}

__global__ void k_wbig(const float* __restrict__ fc_W, const float* __restrict__ B2,
                       const float* __restrict__ B3, float* __restrict__ WB) {
  int g = blockIdx.x * 256 + threadIdx.x;
  int row = g / 96;
  int j0 = (g % 96) * 4;
  if (j0 < 128) {
    *(f4_t*)&WB[row * 384 + j0] = *(const f4_t*)&fc_W[row * 128 + j0];
  } else {
    const float* Bm = (j0 < 256) ? B2 : B3;
    int jj = j0 & 127;
    f4_t acc = {0.f, 0.f, 0.f, 0.f};
    for (int n = 0; n < 128; ++n)
      acc += fc_W[row * 128 + n] * *(const f4_t*)&Bm[n * 128 + jj];
    *(f4_t*)&WB[row * 384 + j0] = acc;
  }
}

__global__ void k_bbig(const float* __restrict__ fc_b, const float* __restrict__ fc2_b,
                       const float* __restrict__ B2, const float* __restrict__ B3,
                       const float* __restrict__ Wq2, const float* __restrict__ Wk3,
                       float* __restrict__ bb) {
  int j = blockIdx.x * 256 + threadIdx.x;
  if (j >= 384) return;
  if (j < 128) { bb[j] = fc_b[j]; return; }
  const float* Bm = (j < 256) ? B2 : B3;
  const float* Wm = (j < 256) ? Wq2 : Wk3;
  int jj = j & 127;
  float acc = 0.f;
  for (int n = 0; n < 128; ++n)
    acc += fc_b[n] * Bm[n * 128 + jj] + fc2_b[n] * Wm[n * 128 + jj];
  bb[j] = acc;
}

__global__ void k_skdf(const float* __restrict__ skill_emb, const float* __restrict__ diff_emb,
                       const float* __restrict__ WB, const float* __restrict__ bb,
                       float* __restrict__ SK, float* __restrict__ DF) {
  int g = blockIdx.x * 256 + threadIdx.x;
  int row = g / 96, j0 = (g % 96) * 4;
  if (blockIdx.y == 0) {
    if (row >= 1002) return;
    f4_t acc = {0.f, 0.f, 0.f, 0.f};
    for (int d = 0; d < 128; ++d)
      acc += skill_emb[row * 128 + d] * *(const f4_t*)&WB[d * 384 + j0];
    *(f4_t*)&SK[row * 384 + j0] = acc;
  } else {
    if (row >= 102) return;
    f4_t acc = *(const f4_t*)&bb[j0];
    for (int d = 0; d < 128; ++d)
      acc += diff_emb[row * 128 + d] * *(const f4_t*)&WB[(128 + d) * 384 + j0];
    *(f4_t*)&DF[row * 384 + j0] = acc;
  }
}

__global__ void k_tv(const float* __restrict__ hints_emb, const float* __restrict__ Wv2,
                     const float* __restrict__ answer_emb, const float* __restrict__ Wv3,
                     float* __restrict__ Tv2, float* __restrict__ Tv3) {
  int g = blockIdx.x * 256 + threadIdx.x;
  if (g < 384) {
    int i = g >> 5, j0 = (g & 31) << 2;
    f4_t acc = {0.f, 0.f, 0.f, 0.f};
    for (int d = 0; d < 128; ++d)
      acc += hints_emb[i * 128 + d] * *(const f4_t*)&Wv2[d * 128 + j0];
    *(f4_t*)&Tv2[i * 128 + j0] = acc;
  } else if (g < 480) {
    int g2 = g - 384;
    int i = g2 >> 5, j0 = (g2 & 31) << 2;
    f4_t acc = {0.f, 0.f, 0.f, 0.f};
    for (int d = 0; d < 128; ++d)
      acc += answer_emb[i * 128 + d] * *(const f4_t*)&Wv3[d * 128 + j0];
    *(f4_t*)&Tv3[i * 128 + j0] = acc;
  }
}

// Pack in-loop weights. 8-wave layout: wave w (0..7) owns cols [16w,16w+16).
// frag flat index f = ((m*4+kk)*8 + w)*64 + lane
// whi: f16 hi (8 u16/frag). wl8: fp8 e4m3 of ((w - f16(w)) * 4096) (8 B/frag).
struct P8 { const float* p[8]; };
__global__ void k_pack(P8 s, u16* __restrict__ whi, u8* __restrict__ wl8) {
  int g = blockIdx.x * 256 + threadIdx.x;   // 128*256 = 32768
  bool lo = (g >= 16384);
  int gg = g & 16383;
  int m = gg >> 11;
  int r = gg & 2047;
  int kk = r >> 9, w = (r >> 6) & 7, l = r & 63;
  const float* src = s.p[m];
  int col = w * 16 + (l & 15);
  int kbase = kk * 32 + ((l >> 4) << 3);
  if (!lo) {
    u16 o[8];
    #pragma unroll
    for (int e = 0; e < 8; ++e) o[e] = f2h_bits(src[(kbase + e) * 128 + col]);
    uint4 u;
    u.x = o[0] | ((u32)o[1] << 16); u.y = o[2] | ((u32)o[3] << 16);
    u.z = o[4] | ((u32)o[5] << 16); u.w = o[6] | ((u32)o[7] << 16);
    *(uint4*)(whi + gg * 8) = u;
  } else {
    float lv[8];
    #pragma unroll
    for (int e = 0; e < 8; ++e) {
      float v = src[(kbase + e) * 128 + col];
      lv[e] = (v - (float)((_Float16)v)) * LO_SCALE;
    }
    uint2 u;
    u.x = pk4f8(lv[0], lv[1], lv[2], lv[3]);
    u.y = pk4f8(lv[4], lv[5], lv[6], lv[7]);
    *(uint2*)(wl8 + (size_t)gg * 8) = u;
  }
}

// ---------------- main recurrent kernel ----------------
// 32 blocks x 512 threads (8 waves, 2 waves/SIMD -> 256-reg cap, co-resident
// wave hides LDS/MFMA/trans latency). Block owns 16 batch rows; wave w owns
// feature cols [16w,16w+16). WH f16-hi register-resident (128 regs); WL fp8
// lo (res*4096) STREAMED from L2 each stage (32 b64 loads, covered by the
// f16 MFMA block). Numerics identical to R13: all acts f16 hi+lo in LDS
// (eff 2^-22) + interleaved fp8 copies for the lo-weight MFMA.

#define RSTRIDE 136   // u16 stride (272 B)
#define RS8 272       // byte stride for interleaved fp8 arrays

__launch_bounds__(512, 2)
__global__ void k_main(const int* __restrict__ skill, const int* __restrict__ answer,
                       const int* __restrict__ diff, const int* __restrict__ hints,
                       const float* __restrict__ SK, const float* __restrict__ DF,
                       const float* __restrict__ Tv2, const float* __restrict__ Tv3,
                       const u16* __restrict__ whi, const u8* __restrict__ wl8,
                       const float* __restrict__ b11p, const float* __restrict__ b12p,
                       const float* __restrict__ b21p, const float* __restrict__ b22p,
                       float* __restrict__ out) {
  __shared__ u16 sh_h[16 * RSTRIDE], sh_hl[16 * RSTRIDE];
  __shared__ u16 sh_c[16 * RSTRIDE], sh_cl[16 * RSTRIDE];
  __shared__ u16 sh_o[16 * RSTRIDE], sh_ol[16 * RSTRIDE];
  __shared__ u16 sh_o3[16 * RSTRIDE], sh_o3l[16 * RSTRIDE];
  __shared__ u8 sh_hc8[16 * RS8];   // [h8(8B) | c8(8B)] per 8-feat block
  __shared__ u8 sh_oo8[16 * RS8];   // [o8(8B) | o38(8B)] per 8-feat block
  __shared__ float sh_red[128];

  const int tid = threadIdx.x;
  const int w = tid >> 6, lane = tid & 63;
  const int row = lane & 15;
  const int fgrp = lane >> 4;
  const int f0 = w * 16 + fgrp * 4;
  const int row_g = blockIdx.x * 16 + row;
  const int r200 = row_g * 200;

  // -------- persistent weights (hi f16 only; lo fp8 streamed) --------
  h8f WH[8][4];
  {
    const int base = w * 64 + lane;
    #pragma unroll
    for (int m = 0; m < 8; ++m)
      #pragma unroll
      for (int kk = 0; kk < 4; ++kk)
        WH[m][kk] = *(const h8f*)&whi[(size_t)(((m * 4 + kk) * 8 + w) * 64 + lane) * 8];
  }
  const u8* wlp = wl8 + (size_t)(w * 64 + lane) * 8;   // + (m*4+kk)*512*8

  // LDS init (h,c hi/lo and fp8 copies = 0)
  for (int i = tid; i < 16 * RSTRIDE / 2; i += 512) {
    ((u32*)sh_h)[i] = 0u; ((u32*)sh_c)[i] = 0u;
    ((u32*)sh_hl)[i] = 0u; ((u32*)sh_cl)[i] = 0u;
  }
  for (int i = tid; i < 16 * RS8 / 4; i += 512) ((u32*)sh_hc8)[i] = 0u;
  if (tid < 16) out[(blockIdx.x * 16 + tid) * 200 + 199] = 0.f;  // y[:,199]=0

  f4_t cst = {0.f, 0.f, 0.f, 0.f};

  int is_cur = skill[r200], id_cur = diff[r200];
  int ih_cur = hints[r200], ia_cur = answer[r200];

  const float inv = 0.088388347648318447f;  // 1/sqrt(128)
  const int rbase = row * RSTRIDE;
  const int widx = rbase + f0;
  int roff[4], boff[4];
  #pragma unroll
  for (int kk = 0; kk < 4; ++kk) {
    roff[kk] = rbase + kk * 32 + fgrp * 8;
    boff[kk] = row * RS8 + (kk * 4 + fgrp) * 16;
  }
  // interleaved fp8 write offset: u32 slot j = w*4+fgrp; block j>>1, half j&1
  const int w8 = row * RS8 + (w * 2 + (fgrp >> 1)) * 16 + (fgrp & 1) * 4;

  __syncthreads();

  for (int t = 0; t < 199; ++t) {
    // ---- S1 top: stream stage-1 WL (L2) + global table loads ----
    long wls[4][4];
    #pragma unroll
    for (int m = 0; m < 4; ++m)
      #pragma unroll
      for (int kk = 0; kk < 4; ++kk)
        wls[m][kk] = *(const long*)(wlp + (size_t)((m * 4 + kk) * 512) * 8);
    f4_t v2  = *(const f4_t*)&Tv2[ih_cur * 128 + f0];
    f4_t v3  = *(const f4_t*)&Tv3[ia_cur * 128 + f0];
    f4_t q2b = *(const f4_t*)&SK[is_cur * 384 + 128 + f0]
             + *(const f4_t*)&DF[id_cur * 384 + 128 + f0];
    f4_t q3b = *(const f4_t*)&SK[is_cur * 384 + 256 + f0]
             + *(const f4_t*)&DF[id_cur * 384 + 256 + f0];
    int n_s = skill[r200 + t + 1];
    int n_d = diff[r200 + t + 1];
    int n_h = hints[r200 + t + 1];
    int n_a = answer[r200 + t + 1];

    // ---- stage 1 f16 MFMAs ----
    f4_t q2 = {0.f,0.f,0.f,0.f}, q3 = {0.f,0.f,0.f,0.f};
    f4_t k3 = {0.f,0.f,0.f,0.f}, k2 = {0.f,0.f,0.f,0.f};
    #pragma unroll
    for (int kk = 0; kk < 4; ++kk) {
      h8f hh = *(const h8f*)&sh_h[roff[kk]];
      h8f hl = *(const h8f*)&sh_hl[roff[kk]];
      h8f ch = *(const h8f*)&sh_c[roff[kk]];
      h8f cl = *(const h8f*)&sh_cl[roff[kk]];
      q2 = MFMAH(WH[0][kk], hh, q2); q2 = MFMAH(WH[0][kk], hl, q2);
      q3 = MFMAH(WH[1][kk], hh, q3); q3 = MFMAH(WH[1][kk], hl, q3);
      k3 = MFMAH(WH[2][kk], hh, k3); k3 = MFMAH(WH[2][kk], hl, k3);
      k2 = MFMAH(WH[3][kk], ch, k2); k2 = MFMAH(WH[3][kk], cl, k2);
    }
    // ---- stage 1 fp8 lo MFMAs (streamed WL now arrived) ----
    f4_t lq2 = {0.f,0.f,0.f,0.f}, lq3 = {0.f,0.f,0.f,0.f};
    f4_t lk3 = {0.f,0.f,0.f,0.f}, lk2 = {0.f,0.f,0.f,0.f};
    #pragma unroll
    for (int kk = 0; kk < 4; ++kk) {
      l2_t hc = *(const l2_t*)&sh_hc8[boff[kk]];
      long h8 = hc[0], c8 = hc[1];
      lq2 = MFMAF8(wls[0][kk], h8, lq2);
      lq3 = MFMAF8(wls[1][kk], h8, lq3);
      lk3 = MFMAF8(wls[2][kk], h8, lk3);
      lk2 = MFMAF8(wls[3][kk], c8, lk2);
    }

    // ---- E1: gates + write o/o3 (f16 hi+lo + interleaved fp8 copy) ----
    {
      float ov[4], o3v[4];
      #pragma unroll
      for (int r = 0; r < 4; ++r) {
        float q2v = (q2[r] + lq2[r] * LO_INV) + q2b[r];
        float q3v = (q3[r] + lq3[r] * LO_INV) + q3b[r];
        float k2v = k2[r] + lk2[r] * LO_INV;
        float k3v = k3[r] + lk3[r] * LO_INV;
        ov[r]  = v2[r] * sigm(q2v * k2v * inv);
        o3v[r] = v3[r] * sigm(q3v * k3v * inv);
      }
      uint2 ph; ph.x = pkrtz(ov[0], ov[1]); ph.y = pkrtz(ov[2], ov[3]);
      *(uint2*)&sh_o[widx] = ph;
      uint2 pl;
      pl.x = pkrtz(ov[0] - h2f((u16)ph.x), ov[1] - h2f((u16)(ph.x >> 16)));
      pl.y = pkrtz(ov[2] - h2f((u16)ph.y), ov[3] - h2f((u16)(ph.y >> 16)));
      *(uint2*)&sh_ol[widx] = pl;
      uint2 p3; p3.x = pkrtz(o3v[0], o3v[1]); p3.y = pkrtz(o3v[2], o3v[3]);
      *(uint2*)&sh_o3[widx] = p3;
      uint2 p3l;
      p3l.x = pkrtz(o3v[0] - h2f((u16)p3.x), o3v[1] - h2f((u16)(p3.x >> 16)));
      p3l.y = pkrtz(o3v[2] - h2f((u16)p3.y), o3v[3] - h2f((u16)(p3.y >> 16)));
      *(uint2*)&sh_o3l[widx] = p3l;
      *(u32*)&sh_oo8[w8]     = pk4f8(ov[0], ov[1], ov[2], ov[3]);
      *(u32*)&sh_oo8[w8 + 8] = pk4f8(o3v[0], o3v[1], o3v[2], o3v[3]);
    }
    __syncthreads();

    // ---- S2 top: stream stage-2 WL + xn tables + biases ----
    long wls2[4][4];
    #pragma unroll
    for (int m = 0; m < 4; ++m)
      #pragma unroll
      for (int kk = 0; kk < 4; ++kk)
        wls2[m][kk] = *(const long*)(wlp + (size_t)(((m + 4) * 4 + kk) * 512) * 8);
    f4_t xn = *(const f4_t*)&SK[n_s * 384 + f0] + *(const f4_t*)&DF[n_d * 384 + f0];
    f4_t b11 = *(const f4_t*)&b11p[f0];
    f4_t b12 = *(const f4_t*)&b12p[f0];
    f4_t b21 = *(const f4_t*)&b21p[f0];
    f4_t b22 = *(const f4_t*)&b22p[f0];

    // ---- stage 2 f16 MFMAs ----
    f4_t a11 = {0.f,0.f,0.f,0.f}, a12 = {0.f,0.f,0.f,0.f};
    f4_t a21 = {0.f,0.f,0.f,0.f}, a22 = {0.f,0.f,0.f,0.f};
    #pragma unroll
    for (int kk = 0; kk < 4; ++kk) {
      h8f of   = *(const h8f*)&sh_o[roff[kk]];
      h8f olf  = *(const h8f*)&sh_ol[roff[kk]];
      h8f o3f  = *(const h8f*)&sh_o3[roff[kk]];
      h8f o3lf = *(const h8f*)&sh_o3l[roff[kk]];
      a11 = MFMAH(WH[4][kk], of, a11);  a11 = MFMAH(WH[4][kk], olf, a11);
      a12 = MFMAH(WH[5][kk], of, a12);  a12 = MFMAH(WH[5][kk], olf, a12);
      a21 = MFMAH(WH[6][kk], o3f, a21); a21 = MFMAH(WH[6][kk], o3lf, a21);
      a22 = MFMAH(WH[7][kk], o3f, a22); a22 = MFMAH(WH[7][kk], o3lf, a22);
    }
    // ---- stage 2 fp8 lo MFMAs ----
    f4_t l11 = {0.f,0.f,0.f,0.f}, l12 = {0.f,0.f,0.f,0.f};
    f4_t l21 = {0.f,0.f,0.f,0.f}, l22 = {0.f,0.f,0.f,0.f};
    #pragma unroll
    for (int kk = 0; kk < 4; ++kk) {
      l2_t oo = *(const l2_t*)&sh_oo8[boff[kk]];
      long o8 = oo[0], o38 = oo[1];
      l11 = MFMAF8(wls2[0][kk], o8, l11);
      l12 = MFMAF8(wls2[1][kk], o8, l12);
      l21 = MFMAF8(wls2[2][kk], o38, l21);
      l22 = MFMAF8(wls2[3][kk], o38, l22);
    }

    // ---- E2: state update + y partial + write h,c (f16 hi+lo + fp8) ----
    float part = 0.f;
    f4_t hv;
    #pragma unroll
    for (int r = 0; r < 4; ++r) {
      float v11 = (a11[r] + l11[r] * LO_INV) + b11[r];
      float v12 = (a12[r] + l12[r] * LO_INV) + b12[r];
      float v21 = (a21[r] + l21[r] * LO_INV) + b21[r];
      float v22 = (a22[r] + l22[r] * LO_INV) + b22[r];
      float g = tanh_f(v11) * sigm(v12);
      cst[r] += g;
      float hh = tanh_f(v21) * sigm(v22) + cst[r];
      hv[r] = hh;
      part += xn[r] * hh;
    }
    part += __shfl_xor(part, 16);
    part += __shfl_xor(part, 32);
    if (lane < 16) sh_red[lane * 8 + w] = part;

    {
      uint2 ph; ph.x = pkrtz(hv[0], hv[1]); ph.y = pkrtz(hv[2], hv[3]);
      *(uint2*)&sh_h[widx] = ph;
      uint2 pl;
      pl.x = pkrtz(hv[0] - h2f((u16)ph.x), hv[1] - h2f((u16)(ph.x >> 16)));
      pl.y = pkrtz(hv[2] - h2f((u16)ph.y), hv[3] - h2f((u16)(ph.y >> 16)));
      *(uint2*)&sh_hl[widx] = pl;
      uint2 pc; pc.x = pkrtz(cst[0], cst[1]); pc.y = pkrtz(cst[2], cst[3]);
      *(uint2*)&sh_c[widx] = pc;
      uint2 pcl;
      pcl.x = pkrtz(cst[0] - h2f((u16)pc.x), cst[1] - h2f((u16)(pc.x >> 16)));
      pcl.y = pkrtz(cst[2] - h2f((u16)pc.y), cst[3] - h2f((u16)(pc.y >> 16)));
      *(uint2*)&sh_cl[widx] = pcl;
      *(u32*)&sh_hc8[w8]     = pk4f8(hv[0], hv[1], hv[2], hv[3]);
      *(u32*)&sh_hc8[w8 + 8] = pk4f8(cst[0], cst[1], cst[2], cst[3]);
    }

    is_cur = n_s; id_cur = n_d; ih_cur = n_h; ia_cur = n_a;
    __syncthreads();

    // ---- Y: finalize y[:, t] (wave 0) ----
    if (w == 0 && lane < 16) {
      const f4_t p0 = *(const f4_t*)&sh_red[lane * 8];
      const f4_t p1 = *(const f4_t*)&sh_red[lane * 8 + 4];
      float s = ((p0[0] + p0[1]) + (p0[2] + p0[3])) + ((p1[0] + p1[1]) + (p1[2] + p1[3]));
      out[(blockIdx.x * 16 + lane) * 200 + t] = sigm(s);
    }
  }
}

// ---------------- launcher ----------------

extern "C" void kernel_launch(void* const* d_in, const int* in_sizes, int n_in,
                              void* d_out, int out_size, void* d_ws, size_t ws_size,
                              hipStream_t stream) {
  const int* skill  = (const int*)d_in[0];
  const int* answer = (const int*)d_in[1];
  const int* diff   = (const int*)d_in[2];
  const int* hints  = (const int*)d_in[3];
  const float* skill_emb  = (const float*)d_in[5];
  const float* answer_emb = (const float*)d_in[6];
  const float* diff_emb   = (const float*)d_in[7];
  const float* hints_emb  = (const float*)d_in[8];
  const float* Wq2 = (const float*)d_in[10];
  const float* Wk2 = (const float*)d_in[11];
  const float* Wv2 = (const float*)d_in[12];
  const float* Wq3 = (const float*)d_in[13];
  const float* Wk3 = (const float*)d_in[14];
  const float* Wv3 = (const float*)d_in[15];
  const float* fc_W  = (const float*)d_in[16];
  const float* fc_b  = (const float*)d_in[17];
  const float* fc2_W = (const float*)d_in[18];
  const float* fc2_b = (const float*)d_in[19];
  const float* f11_W = (const float*)d_in[20];
  const float* f11_b = (const float*)d_in[21];
  const float* f12_W = (const float*)d_in[22];
  const float* f12_b = (const float*)d_in[23];
  const float* f21_W = (const float*)d_in[24];
  const float* f21_b = (const float*)d_in[25];
  const float* f22_W = (const float*)d_in[26];
  const float* f22_b = (const float*)d_in[27];

  float* ws = (float*)d_ws;
  float* A2 = ws + 0;          // 128x128
  float* A3 = ws + 16384;
  float* B2 = ws + 32768;
  float* B3 = ws + 49152;
  float* WB = ws + 65536;      // 256x384
  float* BB = ws + 163840;     // 384
  float* SKt = ws + 164224;    // 1002x384
  float* DFt = ws + 548992;    // 102x384
  float* TV2 = ws + 588160;    // 12x128
  float* TV3 = ws + 589696;    // 3x128
  u16* WHI = (u16*)((char*)d_ws + 2360320);  // 256 KB
  u8* WL8 = (u8*)d_ws + 2622464;             // 128 KB
  float* outp = (float*)d_out;

  k_gemm128<<<16, 256, 0, stream>>>(fc2_W,         Wq2, B2);
  k_gemm128<<<16, 256, 0, stream>>>(fc2_W,         Wk3, B3);
  k_gemm128<<<16, 256, 0, stream>>>(fc2_W + 16384, Wq2, A2);
  k_gemm128<<<16, 256, 0, stream>>>(fc2_W + 16384, Wk3, A3);
  k_wbig<<<96, 256, 0, stream>>>(fc_W, B2, B3, WB);
  k_bbig<<<2, 256, 0, stream>>>(fc_b, fc2_b, B2, B3, Wq2, Wk3, BB);
  k_skdf<<<dim3(376, 2), 256, 0, stream>>>(skill_emb, diff_emb, WB, BB, SKt, DFt);
  k_tv<<<2, 256, 0, stream>>>(hints_emb, Wv2, answer_emb, Wv3, TV2, TV3);
  P8 s;
  s.p[0] = A2; s.p[1] = A3; s.p[2] = Wq3; s.p[3] = Wk2;
  s.p[4] = f11_W; s.p[5] = f12_W; s.p[6] = f21_W; s.p[7] = f22_W;
  k_pack<<<128, 256, 0, stream>>>(s, WHI, WL8);
  k_main<<<32, 512, 0, stream>>>(skill, answer, diff, hints, SKt, DFt, TV2, TV3,
                                 WHI, WL8, f11_b, f12_b, f21_b, f22_b, outp);
}